// Round 2
// baseline (499.648 us; speedup 1.0000x reference)
//
#include <hip/hip_runtime.h>
#include <hip/hip_bf16.h>
#include <type_traits>
#include <utility>

#define B_ 2
#define S_ 2048
#define D_ 1024
#define H_ 16
#define HD_ 64

typedef __attribute__((ext_vector_type(8))) short   s16x8;
typedef __attribute__((ext_vector_type(8))) __bf16  b16x8;
typedef __attribute__((ext_vector_type(4))) float   f32x4;
typedef __attribute__((ext_vector_type(4))) int     i32x4;

// --- MFMA operand-type hedge: accept whichever signature the toolchain has ---
template <typename T, typename = void> struct mfma_takes : std::false_type {};
template <typename T>
struct mfma_takes<T, std::void_t<decltype(__builtin_amdgcn_mfma_f32_16x16x32_bf16(
    std::declval<T>(), std::declval<T>(), std::declval<f32x4>(), 0, 0, 0))>>
    : std::true_type {};
using frag8 = std::conditional_t<mfma_takes<s16x8>::value, s16x8, b16x8>;
static_assert(sizeof(frag8) == 16, "frag8 must be 16B");

__device__ __forceinline__ f32x4 mfma_bf16(frag8 a, frag8 b, f32x4 c) {
  return __builtin_amdgcn_mfma_f32_16x16x32_bf16(a, b, c, 0, 0, 0);
}

__device__ __forceinline__ short f2bf(float f) {  // RTNE f32 -> bf16 bits
  union { float f; unsigned u; } v; v.f = f;
  unsigned u = v.u;
  u += 0x7fffu + ((u >> 16) & 1u);
  return (short)(u >> 16);
}

__device__ __forceinline__ void split_bf(float x, short& hi, short& lo) {
  const short h = f2bf(x);
  union { unsigned u; float f; } hv;
  hv.u = ((unsigned)(unsigned short)h) << 16;
  hi = h;
  lo = f2bf(x - hv.f);
}

__device__ __forceinline__ frag8 ld_frag(const short* p) {
  return __builtin_bit_cast(frag8, *(const i32x4*)p);
}

// ---------------------------------------------------------------------------
// Split-precision NT GEMM (Q/K projections):
// C = (A_f32 @ W_f32^T + bias) * scale, computed with hi/lo bf16 split
// (3 MFMAs per product). Output written as hi & lo bf16 planes in [B,H,S,Hd].
// ---------------------------------------------------------------------------
__global__ __launch_bounds__(256)
void gemm_nt_split(const float* __restrict__ Ap, const float* __restrict__ W,
                   const float* __restrict__ bias, short* __restrict__ OutHi,
                   short* __restrict__ OutLo, float scale) {
  constexpr int K = 1024;
  __shared__ __align__(16) short Ah[64][40], Al[64][40];
  __shared__ __align__(16) short Bh[64][40], Bl[64][40];

  const int t = threadIdx.x;
  const int bm = blockIdx.y, bn = blockIdx.x;
  const int srow = t >> 2;            // 0..63
  const int skseg = (t & 3) << 3;     // 0,8,16,24
  const int wave = t >> 6, lane = t & 63;
  const int laneN = lane & 15, quad = lane >> 4;

  f32x4 acc[4];
#pragma unroll
  for (int i = 0; i < 4; ++i)
#pragma unroll
    for (int j = 0; j < 4; ++j) acc[i][j] = 0.f;

  const size_t arow = (size_t)(bm * 64 + srow);
  const size_t brow = (size_t)(bn * 64 + srow);

  for (int kk = 0; kk < K; kk += 32) {
    __syncthreads();
    {
      const float* Ag = Ap + arow * K + kk + skseg;
      float4 a0 = *(const float4*)Ag;
      float4 a1 = *(const float4*)(Ag + 4);
      float xs[8] = { a0.x, a0.y, a0.z, a0.w, a1.x, a1.y, a1.z, a1.w };
      short hi[8], lo[8];
#pragma unroll
      for (int j = 0; j < 8; ++j) split_bf(xs[j], hi[j], lo[j]);
      i32x4 ph, pl;
      __builtin_memcpy(&ph, hi, 16); __builtin_memcpy(&pl, lo, 16);
      *(i32x4*)&Ah[srow][skseg] = ph;
      *(i32x4*)&Al[srow][skseg] = pl;
    }
    {
      const float* Bg = W + brow * K + kk + skseg;
      float4 b0 = *(const float4*)Bg;
      float4 b1 = *(const float4*)(Bg + 4);
      float xs[8] = { b0.x, b0.y, b0.z, b0.w, b1.x, b1.y, b1.z, b1.w };
      short hi[8], lo[8];
#pragma unroll
      for (int j = 0; j < 8; ++j) split_bf(xs[j], hi[j], lo[j]);
      i32x4 ph, pl;
      __builtin_memcpy(&ph, hi, 16); __builtin_memcpy(&pl, lo, 16);
      *(i32x4*)&Bh[srow][skseg] = ph;
      *(i32x4*)&Bl[srow][skseg] = pl;
    }
    __syncthreads();

    frag8 ah = ld_frag(&Ah[wave * 16 + laneN][quad * 8]);
    frag8 al = ld_frag(&Al[wave * 16 + laneN][quad * 8]);
#pragma unroll
    for (int nt = 0; nt < 4; ++nt) {
      frag8 bh = ld_frag(&Bh[nt * 16 + laneN][quad * 8]);
      frag8 bl = ld_frag(&Bl[nt * 16 + laneN][quad * 8]);
      acc[nt] = mfma_bf16(ah, bh, acc[nt]);
      acc[nt] = mfma_bf16(ah, bl, acc[nt]);
      acc[nt] = mfma_bf16(al, bh, acc[nt]);
    }
  }

  // Epilogue. C/D layout: col = lane&15, row = quad*4 + reg.
#pragma unroll
  for (int nt = 0; nt < 4; ++nt) {
#pragma unroll
    for (int r = 0; r < 4; ++r) {
      const int rowg = bm * 64 + wave * 16 + quad * 4 + r;
      const int colg = bn * 64 + nt * 16 + laneN;
      const float v = (acc[nt][r] + bias[colg]) * scale;
      const int b = rowg >> 11, s = rowg & 2047;
      const int h = colg >> 6, hd = colg & 63;
      const size_t idx = (((size_t)(b * H_ + h)) * S_ + s) * HD_ + hd;
      short hi, lo; split_bf(v, hi, lo);
      OutHi[idx] = hi; OutLo[idx] = lo;
    }
  }
}

// ---------------------------------------------------------------------------
// Plain bf16 NT GEMM (V projection, O projection).
// AMODE 0: A fp32; AMODE 1: A bf16.
// OMODE 0: fp32 flat [M,N] out; OMODE 1: bf16 out in [B,H,S,Hd].
// ---------------------------------------------------------------------------
template <int AMODE, int OMODE>
__global__ __launch_bounds__(256)
void gemm_nt(const void* __restrict__ Ap, const float* __restrict__ W,
             const float* __restrict__ bias, void* __restrict__ Out) {
  constexpr int K = 1024;
  __shared__ __align__(16) short As[64][40];
  __shared__ __align__(16) short Bs[64][40];

  const int t = threadIdx.x;
  const int bm = blockIdx.y, bn = blockIdx.x;
  const int srow = t >> 2;
  const int skseg = (t & 3) << 3;
  const int wave = t >> 6, lane = t & 63;
  const int laneN = lane & 15, quad = lane >> 4;

  f32x4 acc[4];
#pragma unroll
  for (int i = 0; i < 4; ++i)
#pragma unroll
    for (int j = 0; j < 4; ++j) acc[i][j] = 0.f;

  const size_t arow = (size_t)(bm * 64 + srow);
  const size_t brow = (size_t)(bn * 64 + srow);

  for (int kk = 0; kk < K; kk += 32) {
    __syncthreads();
    if (AMODE == 0) {
      const float* Ag = (const float*)Ap + arow * K + kk + skseg;
      float4 a0 = *(const float4*)Ag;
      float4 a1 = *(const float4*)(Ag + 4);
      short tmp[8] = { f2bf(a0.x), f2bf(a0.y), f2bf(a0.z), f2bf(a0.w),
                       f2bf(a1.x), f2bf(a1.y), f2bf(a1.z), f2bf(a1.w) };
      i32x4 pk; __builtin_memcpy(&pk, tmp, 16);
      *(i32x4*)&As[srow][skseg] = pk;
    } else {
      const short* Ag = (const short*)Ap + arow * K + kk + skseg;
      *(i32x4*)&As[srow][skseg] = *(const i32x4*)Ag;
    }
    {
      const float* Bg = W + brow * K + kk + skseg;
      float4 b0 = *(const float4*)Bg;
      float4 b1 = *(const float4*)(Bg + 4);
      short tmp[8] = { f2bf(b0.x), f2bf(b0.y), f2bf(b0.z), f2bf(b0.w),
                       f2bf(b1.x), f2bf(b1.y), f2bf(b1.z), f2bf(b1.w) };
      i32x4 pk; __builtin_memcpy(&pk, tmp, 16);
      *(i32x4*)&Bs[srow][skseg] = pk;
    }
    __syncthreads();

    frag8 aF = ld_frag(&As[wave * 16 + laneN][quad * 8]);
#pragma unroll
    for (int nt = 0; nt < 4; ++nt) {
      frag8 bF = ld_frag(&Bs[nt * 16 + laneN][quad * 8]);
      acc[nt] = mfma_bf16(aF, bF, acc[nt]);
    }
  }

#pragma unroll
  for (int nt = 0; nt < 4; ++nt) {
#pragma unroll
    for (int r = 0; r < 4; ++r) {
      const int rowg = bm * 64 + wave * 16 + quad * 4 + r;
      const int colg = bn * 64 + nt * 16 + laneN;
      const float v = acc[nt][r] + bias[colg];
      if (OMODE == 0) {
        ((float*)Out)[(size_t)rowg * 1024 + colg] = v;
      } else {
        const int b = rowg >> 11, s = rowg & 2047;
        const int h = colg >> 6, hd = colg & 63;
        ((short*)Out)[(((size_t)(b * H_ + h)) * S_ + s) * HD_ + hd] = f2bf(v);
      }
    }
  }
}

// ---------------------------------------------------------------------------
// Flash attention with split-precision QK^T. Q pre-scaled by 8 (hi/lo planes).
// ---------------------------------------------------------------------------
__global__ __launch_bounds__(256)
void attn(const short* __restrict__ Qh_, const short* __restrict__ Ql_,
          const short* __restrict__ Kh_, const short* __restrict__ Kl_,
          const short* __restrict__ Vw, short* __restrict__ Ow) {
  __shared__ __align__(16) short Qsh[64][72], Qsl[64][72];
  __shared__ __align__(16) short Ksh[64][72], Ksl[64][72];
  __shared__ __align__(16) short Vt[64][72];      // transposed: [d][kpos]
  __shared__ __align__(16) short Ps[4][16][72];   // per-wave P strip

  const int qt = blockIdx.x, h = blockIdx.y, b = blockIdx.z;
  const size_t head = ((size_t)b * H_ + h) * (size_t)S_ * HD_;
  const short* Qhp = Qh_ + head + (size_t)qt * 64 * HD_;
  const short* Qlp = Ql_ + head + (size_t)qt * 64 * HD_;
  const short* Khp = Kh_ + head;
  const short* Klp = Kl_ + head;
  const short* Vh  = Vw + head;

  const int t = threadIdx.x;
  const int wave = t >> 6, lane = t & 63;
  const int laneN = lane & 15, quad = lane >> 4;
  const int srow = t >> 2;           // 0..63
  const int scol = (t & 3) << 4;     // 0,16,32,48

  { // stage Q tiles (hi+lo)
    const short* sh = Qhp + srow * HD_ + scol;
    *(i32x4*)&Qsh[srow][scol]     = *(const i32x4*)sh;
    *(i32x4*)&Qsh[srow][scol + 8] = *(const i32x4*)(sh + 8);
    const short* sl = Qlp + srow * HD_ + scol;
    *(i32x4*)&Qsl[srow][scol]     = *(const i32x4*)sl;
    *(i32x4*)&Qsl[srow][scol + 8] = *(const i32x4*)(sl + 8);
  }
  __syncthreads();
  const frag8 qh0 = ld_frag(&Qsh[wave * 16 + laneN][quad * 8]);
  const frag8 qh1 = ld_frag(&Qsh[wave * 16 + laneN][32 + quad * 8]);
  const frag8 ql0 = ld_frag(&Qsl[wave * 16 + laneN][quad * 8]);
  const frag8 ql1 = ld_frag(&Qsl[wave * 16 + laneN][32 + quad * 8]);

  f32x4 o[4];
  float m_r[4], l_r[4];
#pragma unroll
  for (int i = 0; i < 4; ++i) {
    m_r[i] = -1e30f; l_r[i] = 0.f;
#pragma unroll
    for (int j = 0; j < 4; ++j) o[i][j] = 0.f;
  }

  for (int kt = 0; kt < 32; ++kt) {
    __syncthreads();
    { // stage K (hi+lo) + V (transposed)
      const short* kh = Khp + (size_t)(kt * 64 + srow) * HD_ + scol;
      *(i32x4*)&Ksh[srow][scol]     = *(const i32x4*)kh;
      *(i32x4*)&Ksh[srow][scol + 8] = *(const i32x4*)(kh + 8);
      const short* kl = Klp + (size_t)(kt * 64 + srow) * HD_ + scol;
      *(i32x4*)&Ksl[srow][scol]     = *(const i32x4*)kl;
      *(i32x4*)&Ksl[srow][scol + 8] = *(const i32x4*)(kl + 8);
      const short* vsrc = Vh + (size_t)(kt * 64 + srow) * HD_ + scol;
      short vt[16];
      i32x4 v0 = *(const i32x4*)vsrc;
      i32x4 v1 = *(const i32x4*)(vsrc + 8);
      __builtin_memcpy(&vt[0], &v0, 16);
      __builtin_memcpy(&vt[8], &v1, 16);
#pragma unroll
      for (int j = 0; j < 16; ++j) Vt[scol + j][srow] = vt[j];
    }
    __syncthreads();

    // scores: S[16q x 64k] per wave, split-precision
    f32x4 s[4];
#pragma unroll
    for (int nt = 0; nt < 4; ++nt) {
#pragma unroll
      for (int j = 0; j < 4; ++j) s[nt][j] = 0.f;
      frag8 kh0 = ld_frag(&Ksh[nt * 16 + laneN][quad * 8]);
      frag8 kh1 = ld_frag(&Ksh[nt * 16 + laneN][32 + quad * 8]);
      frag8 kl0 = ld_frag(&Ksl[nt * 16 + laneN][quad * 8]);
      frag8 kl1 = ld_frag(&Ksl[nt * 16 + laneN][32 + quad * 8]);
      s[nt] = mfma_bf16(qh0, kh0, s[nt]);
      s[nt] = mfma_bf16(qh0, kl0, s[nt]);
      s[nt] = mfma_bf16(ql0, kh0, s[nt]);
      s[nt] = mfma_bf16(qh1, kh1, s[nt]);
      s[nt] = mfma_bf16(qh1, kl1, s[nt]);
      s[nt] = mfma_bf16(ql1, kh1, s[nt]);
    }

    // online softmax per row (row = quad*4 + r, cols spread over 16 lanes)
#pragma unroll
    for (int r = 0; r < 4; ++r) {
      float mx = fmaxf(fmaxf(s[0][r], s[1][r]), fmaxf(s[2][r], s[3][r]));
      mx = fmaxf(mx, __shfl_xor(mx, 1));
      mx = fmaxf(mx, __shfl_xor(mx, 2));
      mx = fmaxf(mx, __shfl_xor(mx, 4));
      mx = fmaxf(mx, __shfl_xor(mx, 8));
      const float mn = fmaxf(m_r[r], mx);
      const float al = __expf(m_r[r] - mn);
      m_r[r] = mn;
      float rs = 0.f;
#pragma unroll
      for (int nt = 0; nt < 4; ++nt) {
        const float p = __expf(s[nt][r] - mn);
        s[nt][r] = p; rs += p;
      }
      rs += __shfl_xor(rs, 1);
      rs += __shfl_xor(rs, 2);
      rs += __shfl_xor(rs, 4);
      rs += __shfl_xor(rs, 8);
      l_r[r] = l_r[r] * al + rs;
#pragma unroll
      for (int dt = 0; dt < 4; ++dt) o[dt][r] *= al;
    }

    // P: C-layout -> LDS -> A-layout
#pragma unroll
    for (int nt = 0; nt < 4; ++nt)
#pragma unroll
      for (int r = 0; r < 4; ++r)
        Ps[wave][quad * 4 + r][nt * 16 + laneN] = f2bf(s[nt][r]);
    __syncthreads();

    const frag8 p0 = ld_frag(&Ps[wave][laneN][quad * 8]);
    const frag8 p1 = ld_frag(&Ps[wave][laneN][32 + quad * 8]);
#pragma unroll
    for (int dt = 0; dt < 4; ++dt) {
      frag8 v0 = ld_frag(&Vt[dt * 16 + laneN][quad * 8]);
      frag8 v1 = ld_frag(&Vt[dt * 16 + laneN][32 + quad * 8]);
      o[dt] = mfma_bf16(p0, v0, o[dt]);
      o[dt] = mfma_bf16(p1, v1, o[dt]);
    }
  }

  // epilogue: O /= l, store bf16 [B,S,D]
#pragma unroll
  for (int r = 0; r < 4; ++r) {
    const float inv = 1.0f / l_r[r];
    const int sg = qt * 64 + wave * 16 + quad * 4 + r;
#pragma unroll
    for (int dt = 0; dt < 4; ++dt) {
      const int d = dt * 16 + laneN;
      Ow[((size_t)b * S_ + sg) * D_ + h * HD_ + d] = f2bf(o[dt][r] * inv);
    }
  }
}

// ---------------------------------------------------------------------------
extern "C" void kernel_launch(void* const* d_in, const int* in_sizes, int n_in,
                              void* d_out, int out_size, void* d_ws, size_t ws_size,
                              hipStream_t stream) {
  const float* q  = (const float*)d_in[0];
  const float* k  = (const float*)d_in[1];
  const float* v  = (const float*)d_in[2];
  const float* Wq = (const float*)d_in[3];
  const float* bq = (const float*)d_in[4];
  const float* Wk = (const float*)d_in[5];
  const float* bk = (const float*)d_in[6];
  const float* Wv = (const float*)d_in[7];
  const float* bv = (const float*)d_in[8];
  const float* Wo = (const float*)d_in[9];
  const float* bo = (const float*)d_in[10];

  const size_t HTOK = (size_t)B_ * H_ * S_ * HD_;  // 4,194,304
  short* Qhi = (short*)d_ws;
  short* Qlo = Qhi + HTOK;
  short* Khi = Qlo + HTOK;
  short* Klo = Khi + HTOK;
  short* Vw  = Klo + HTOK;
  short* Ow  = Vw + HTOK;

  dim3 blk(256);
  dim3 gg(16, 64);  // N-tiles x M-tiles

  // scores = (q.k) * 8  -> fold x8 into Q projection (exact scaling)
  gemm_nt_split<<<gg, blk, 0, stream>>>(q, Wq, bq, Qhi, Qlo, 8.0f);
  gemm_nt_split<<<gg, blk, 0, stream>>>(k, Wk, bk, Khi, Klo, 1.0f);
  gemm_nt<0, 1><<<gg, blk, 0, stream>>>((const void*)v, Wv, bv, (void*)Vw);

  attn<<<dim3(S_ / 64, H_, B_), blk, 0, stream>>>(Qhi, Qlo, Khi, Klo, Vw, Ow);

  gemm_nt<1, 0><<<gg, blk, 0, stream>>>((const void*)Ow, Wo, bo, d_out);
}

// Round 3
// 417.182 us; speedup vs baseline: 1.1977x; 1.1977x over previous
//
#include <hip/hip_runtime.h>
#include <hip/hip_bf16.h>
#include <type_traits>
#include <utility>

#define B_ 2
#define S_ 2048
#define D_ 1024
#define H_ 16
#define HD_ 64
#define KDIM 1024

typedef __attribute__((ext_vector_type(8))) short   s16x8;
typedef __attribute__((ext_vector_type(8))) __bf16  b16x8;
typedef __attribute__((ext_vector_type(4))) float   f32x4;
typedef __attribute__((ext_vector_type(4))) int     i32x4;

// --- MFMA operand-type hedge ---
template <typename T, typename = void> struct mfma_takes : std::false_type {};
template <typename T>
struct mfma_takes<T, std::void_t<decltype(__builtin_amdgcn_mfma_f32_16x16x32_bf16(
    std::declval<T>(), std::declval<T>(), std::declval<f32x4>(), 0, 0, 0))>>
    : std::true_type {};
using frag8 = std::conditional_t<mfma_takes<s16x8>::value, s16x8, b16x8>;

__device__ __forceinline__ f32x4 mfma_bf16(frag8 a, frag8 b, f32x4 c) {
  return __builtin_amdgcn_mfma_f32_16x16x32_bf16(a, b, c, 0, 0, 0);
}

__device__ __forceinline__ short f2bf(float f) {  // RTNE f32 -> bf16 bits
  union { float f; unsigned u; } v; v.f = f;
  unsigned u = v.u;
  u += 0x7fffu + ((u >> 16) & 1u);
  return (short)(u >> 16);
}
__device__ __forceinline__ void split_bf(float x, short& hi, short& lo) {
  const short h = f2bf(x);
  union { unsigned u; float f; } hv;
  hv.u = ((unsigned)(unsigned short)h) << 16;
  hi = h; lo = f2bf(x - hv.f);
}
__device__ __forceinline__ frag8 ld_frag(const short* p) {
  return __builtin_bit_cast(frag8, *(const i32x4*)p);
}

typedef __attribute__((address_space(1))) const void gvoid;
typedef __attribute__((address_space(3))) void lvoid;
__device__ __forceinline__ void async_copy16(const void* g, void* l) {
  __builtin_amdgcn_global_load_lds((gvoid*)g, (lvoid*)l, 16, 0, 0);
}

// ---------------------------------------------------------------------------
// Elementwise converts (8 elems/thread)
// ---------------------------------------------------------------------------
__global__ __launch_bounds__(256) void conv_split(const float* __restrict__ in,
                                                  short* __restrict__ hi,
                                                  short* __restrict__ lo) {
  const int i = (blockIdx.x * 256 + threadIdx.x) * 8;
  float4 a0 = *(const float4*)(in + i);
  float4 a1 = *(const float4*)(in + i + 4);
  float xs[8] = { a0.x, a0.y, a0.z, a0.w, a1.x, a1.y, a1.z, a1.w };
  short h[8], l[8];
#pragma unroll
  for (int j = 0; j < 8; ++j) split_bf(xs[j], h[j], l[j]);
  i32x4 ph, pl;
  __builtin_memcpy(&ph, h, 16); __builtin_memcpy(&pl, l, 16);
  *(i32x4*)(hi + i) = ph; *(i32x4*)(lo + i) = pl;
}

__global__ __launch_bounds__(256) void conv_plain(const float* __restrict__ in,
                                                  short* __restrict__ out) {
  const int i = (blockIdx.x * 256 + threadIdx.x) * 8;
  float4 a0 = *(const float4*)(in + i);
  float4 a1 = *(const float4*)(in + i + 4);
  short h[8] = { f2bf(a0.x), f2bf(a0.y), f2bf(a0.z), f2bf(a0.w),
                 f2bf(a1.x), f2bf(a1.y), f2bf(a1.z), f2bf(a1.w) };
  i32x4 ph; __builtin_memcpy(&ph, h, 16);
  *(i32x4*)(out + i) = ph;
}

// ---------------------------------------------------------------------------
// bf16 NT GEMM, tile 128(M)x64(N), BK=32, global_load_lds staging with
// XOR-swizzled LDS ([row][kgrp^((row>>1)&3)]) so frag ds_read_b128 are ~2-way.
// SPLIT: A/B have hi+lo planes, 3 MFMAs per product.
// OUT: 0 = fp32 flat [M,1024] (+bias), 1 = split bf16 planes [B,H,S,Hd]
// (scaled, +bias), 2 = bf16 Vt [B,H,Hd,S] (+bias).
// ---------------------------------------------------------------------------
template <int SPLIT, int OUT>
__global__ __launch_bounds__(256)
void gemm128(const short* __restrict__ Ahp, const short* __restrict__ Alp,
             const short* __restrict__ Bhp, const short* __restrict__ Blp,
             const float* __restrict__ bias, void* __restrict__ OutA,
             void* __restrict__ OutB, float scale) {
  __shared__ short As[128 * 32];
  __shared__ short Bs[64 * 32];
  __shared__ short As2[SPLIT ? 128 * 32 : 16];
  __shared__ short Bs2[SPLIT ? 64 * 32 : 16];

  const int t = threadIdx.x, wave = t >> 6, lane = t & 63;
  const int laneN = lane & 15, quad = lane >> 4;
  const int bn = blockIdx.x, bm = blockIdx.y;

  f32x4 acc[4][2];
#pragma unroll
  for (int i = 0; i < 4; ++i)
#pragma unroll
    for (int j = 0; j < 2; ++j)
#pragma unroll
      for (int r = 0; r < 4; ++r) acc[i][j][r] = 0.f;

  for (int kk = 0; kk < KDIM; kk += 32) {
    if (kk) __syncthreads();
    // ---- A staging: 2 insts/thread (128 rows x 4 kgrps = 512 groups)
#pragma unroll
    for (int j = 0; j < 2; ++j) {
      const int g = (j * 4 + wave) * 64 + lane;
      const int row = g >> 2;
      const int ks = (g & 3) ^ ((row >> 1) & 3);
      const short* gp = Ahp + (size_t)(bm * 128 + row) * KDIM + kk + ks * 8;
      async_copy16(gp, (short*)As + (j * 4 + wave) * 512);
      if (SPLIT) {
        const short* gp2 = Alp + (size_t)(bm * 128 + row) * KDIM + kk + ks * 8;
        async_copy16(gp2, (short*)As2 + (j * 4 + wave) * 512);
      }
    }
    // ---- B staging: 1 inst/thread (64 rows x 4 kgrps = 256 groups)
    {
      const int g = wave * 64 + lane;
      const int row = g >> 2;
      const int ks = (g & 3) ^ ((row >> 1) & 3);
      const short* gp = Bhp + (size_t)(bn * 64 + row) * KDIM + kk + ks * 8;
      async_copy16(gp, (short*)Bs + wave * 512);
      if (SPLIT) {
        const short* gp2 = Blp + (size_t)(bn * 64 + row) * KDIM + kk + ks * 8;
        async_copy16(gp2, (short*)Bs2 + wave * 512);
      }
    }
    __syncthreads();  // drains vmcnt (global_load_lds) per compiler semantics

    frag8 aH[4], bH[2], aL[4], bL[2];
#pragma unroll
    for (int mi = 0; mi < 4; ++mi) {
      const int row = (wave & 1) * 64 + mi * 16 + laneN;
      const int off = row * 32 + ((quad ^ ((row >> 1) & 3)) * 8);
      aH[mi] = ld_frag(As + off);
      if (SPLIT) aL[mi] = ld_frag(As2 + off);
    }
#pragma unroll
    for (int ni = 0; ni < 2; ++ni) {
      const int row = (wave >> 1) * 32 + ni * 16 + laneN;
      const int off = row * 32 + ((quad ^ ((row >> 1) & 3)) * 8);
      bH[ni] = ld_frag(Bs + off);
      if (SPLIT) bL[ni] = ld_frag(Bs2 + off);
    }
#pragma unroll
    for (int mi = 0; mi < 4; ++mi)
#pragma unroll
      for (int ni = 0; ni < 2; ++ni) {
        acc[mi][ni] = mfma_bf16(aH[mi], bH[ni], acc[mi][ni]);
        if (SPLIT) {
          acc[mi][ni] = mfma_bf16(aH[mi], bL[ni], acc[mi][ni]);
          acc[mi][ni] = mfma_bf16(aL[mi], bH[ni], acc[mi][ni]);
        }
      }
  }

  // Epilogue. C/D: col = lane&15, row = quad*4 + reg.
#pragma unroll
  for (int mi = 0; mi < 4; ++mi)
#pragma unroll
    for (int ni = 0; ni < 2; ++ni)
#pragma unroll
      for (int r = 0; r < 4; ++r) {
        const int rowg = bm * 128 + (wave & 1) * 64 + mi * 16 + quad * 4 + r;
        const int colg = bn * 64 + (wave >> 1) * 32 + ni * 16 + laneN;
        float v = acc[mi][ni][r] + bias[colg];
        if (OUT == 0) {
          ((float*)OutA)[(size_t)rowg * 1024 + colg] = v;
        } else {
          const int b = rowg >> 11, s = rowg & 2047;
          const int h = colg >> 6, hd = colg & 63;
          if (OUT == 1) {
            v *= scale;
            const size_t idx = (((size_t)(b * H_ + h)) * S_ + s) * HD_ + hd;
            short hi, lo; split_bf(v, hi, lo);
            ((short*)OutA)[idx] = hi; ((short*)OutB)[idx] = lo;
          } else {  // Vt [B,H,Hd,S]
            const size_t idx = (((size_t)(b * H_ + h)) * HD_ + hd) * S_ + s;
            ((short*)OutA)[idx] = f2bf(v);
          }
        }
      }
}

// ---------------------------------------------------------------------------
// Flash attention: 128 q-rows/block (2 sets of 16 per wave), split QK^T,
// V pre-transposed in global ([B,H,Hd,S]), softmax in exp2 domain
// (Q pre-scaled by 8*log2e). Q frags straight from global. LDS 45KB.
// ---------------------------------------------------------------------------
__global__ __launch_bounds__(256)
void attn(const short* __restrict__ Qh_, const short* __restrict__ Ql_,
          const short* __restrict__ Kh_, const short* __restrict__ Kl_,
          const short* __restrict__ Vt_, short* __restrict__ Ow) {
  __shared__ __align__(16) short Ksh[64][72];
  __shared__ __align__(16) short Ksl[64][72];
  __shared__ __align__(16) short Vts[64][72];     // [d][kpos]
  __shared__ __align__(16) short Ps[4][32][72];   // per-wave P strip

  const int qt = blockIdx.x, h = blockIdx.y, b = blockIdx.z;
  const size_t head = ((size_t)b * H_ + h) * (size_t)S_ * HD_;

  const int t = threadIdx.x;
  const int wave = t >> 6, lane = t & 63;
  const int laneN = lane & 15, quad = lane >> 4;
  const int srow = t >> 2;           // 0..63
  const int scol = (t & 3) << 4;     // 0,16,32,48

  // Q frags direct from global: rows qt*128 + wave*32 + set*16 + laneN
  frag8 qh[2][2], ql[2][2];
#pragma unroll
  for (int set = 0; set < 2; ++set) {
    const size_t row = (size_t)qt * 128 + wave * 32 + set * 16 + laneN;
#pragma unroll
    for (int half = 0; half < 2; ++half) {
      qh[set][half] = ld_frag(Qh_ + head + row * HD_ + half * 32 + quad * 8);
      ql[set][half] = ld_frag(Ql_ + head + row * HD_ + half * 32 + quad * 8);
    }
  }

  f32x4 o[2][4];
  float m_r[2][4], l_r[2][4];
#pragma unroll
  for (int st = 0; st < 2; ++st)
#pragma unroll
    for (int i = 0; i < 4; ++i) {
      m_r[st][i] = -1e30f; l_r[st][i] = 0.f;
#pragma unroll
      for (int j = 0; j < 4; ++j) o[st][i][j] = 0.f;
    }

  for (int kt = 0; kt < 32; ++kt) {
    if (kt) __syncthreads();
    { // stage K hi/lo [kpos][d] and Vt [d][kpos]
      const short* kh = Kh_ + head + (size_t)(kt * 64 + srow) * HD_ + scol;
      *(i32x4*)&Ksh[srow][scol]     = *(const i32x4*)kh;
      *(i32x4*)&Ksh[srow][scol + 8] = *(const i32x4*)(kh + 8);
      const short* kl = Kl_ + head + (size_t)(kt * 64 + srow) * HD_ + scol;
      *(i32x4*)&Ksl[srow][scol]     = *(const i32x4*)kl;
      *(i32x4*)&Ksl[srow][scol + 8] = *(const i32x4*)(kl + 8);
      const short* vs = Vt_ + head + (size_t)srow * S_ + kt * 64 + scol;
      *(i32x4*)&Vts[srow][scol]     = *(const i32x4*)vs;
      *(i32x4*)&Vts[srow][scol + 8] = *(const i32x4*)(vs + 8);
    }
    __syncthreads();

    // scores for both q-sets
    f32x4 s[2][4];
#pragma unroll
    for (int nt = 0; nt < 4; ++nt) {
      frag8 kh0 = ld_frag(&Ksh[nt * 16 + laneN][quad * 8]);
      frag8 kh1 = ld_frag(&Ksh[nt * 16 + laneN][32 + quad * 8]);
      frag8 kl0 = ld_frag(&Ksl[nt * 16 + laneN][quad * 8]);
      frag8 kl1 = ld_frag(&Ksl[nt * 16 + laneN][32 + quad * 8]);
#pragma unroll
      for (int st = 0; st < 2; ++st) {
        f32x4 acc;
#pragma unroll
        for (int j = 0; j < 4; ++j) acc[j] = 0.f;
        acc = mfma_bf16(qh[st][0], kh0, acc);
        acc = mfma_bf16(qh[st][0], kl0, acc);
        acc = mfma_bf16(ql[st][0], kh0, acc);
        acc = mfma_bf16(qh[st][1], kh1, acc);
        acc = mfma_bf16(qh[st][1], kl1, acc);
        acc = mfma_bf16(ql[st][1], kh1, acc);
        s[st][nt] = acc;
      }
    }

    // online softmax (exp2 domain), rows = quad*4+r per set
#pragma unroll
    for (int st = 0; st < 2; ++st)
#pragma unroll
      for (int r = 0; r < 4; ++r) {
        float mx = fmaxf(fmaxf(s[st][0][r], s[st][1][r]),
                         fmaxf(s[st][2][r], s[st][3][r]));
        mx = fmaxf(mx, __shfl_xor(mx, 1));
        mx = fmaxf(mx, __shfl_xor(mx, 2));
        mx = fmaxf(mx, __shfl_xor(mx, 4));
        mx = fmaxf(mx, __shfl_xor(mx, 8));
        const float mn = fmaxf(m_r[st][r], mx);
        const float al = exp2f(m_r[st][r] - mn);
        m_r[st][r] = mn;
        float rs = 0.f;
#pragma unroll
        for (int nt = 0; nt < 4; ++nt) {
          const float p = exp2f(s[st][nt][r] - mn);
          s[st][nt][r] = p; rs += p;
        }
        rs += __shfl_xor(rs, 1);
        rs += __shfl_xor(rs, 2);
        rs += __shfl_xor(rs, 4);
        rs += __shfl_xor(rs, 8);
        l_r[st][r] = l_r[st][r] * al + rs;
#pragma unroll
        for (int dt = 0; dt < 4; ++dt) o[st][dt][r] *= al;
      }

    // P: C-layout -> LDS (wave-private strip, no barrier needed)
#pragma unroll
    for (int st = 0; st < 2; ++st)
#pragma unroll
      for (int nt = 0; nt < 4; ++nt)
#pragma unroll
        for (int r = 0; r < 4; ++r)
          Ps[wave][st * 16 + quad * 4 + r][nt * 16 + laneN] = f2bf(s[st][nt][r]);
    asm volatile("s_waitcnt lgkmcnt(0)" ::: "memory");

#pragma unroll
    for (int st = 0; st < 2; ++st) {
      const frag8 p0 = ld_frag(&Ps[wave][st * 16 + laneN][quad * 8]);
      const frag8 p1 = ld_frag(&Ps[wave][st * 16 + laneN][32 + quad * 8]);
#pragma unroll
      for (int dt = 0; dt < 4; ++dt) {
        frag8 v0 = ld_frag(&Vts[dt * 16 + laneN][quad * 8]);
        frag8 v1 = ld_frag(&Vts[dt * 16 + laneN][32 + quad * 8]);
        o[st][dt] = mfma_bf16(p0, v0, o[st][dt]);
        o[st][dt] = mfma_bf16(p1, v1, o[st][dt]);
      }
    }
  }

  // epilogue: O /= l, store bf16 [B,S,D]
#pragma unroll
  for (int st = 0; st < 2; ++st)
#pragma unroll
    for (int r = 0; r < 4; ++r) {
      const float inv = 1.0f / l_r[st][r];
      const int sg = qt * 128 + wave * 32 + st * 16 + quad * 4 + r;
#pragma unroll
      for (int dt = 0; dt < 4; ++dt) {
        const int d = dt * 16 + laneN;
        Ow[((size_t)b * S_ + sg) * D_ + h * HD_ + d] = f2bf(o[st][dt][r] * inv);
      }
    }
}

// ---------------------------------------------------------------------------
extern "C" void kernel_launch(void* const* d_in, const int* in_sizes, int n_in,
                              void* d_out, int out_size, void* d_ws, size_t ws_size,
                              hipStream_t stream) {
  const float* q  = (const float*)d_in[0];
  const float* k  = (const float*)d_in[1];
  const float* v  = (const float*)d_in[2];
  const float* Wq = (const float*)d_in[3];
  const float* bq = (const float*)d_in[4];
  const float* Wk = (const float*)d_in[5];
  const float* bk = (const float*)d_in[6];
  const float* Wv = (const float*)d_in[7];
  const float* bv = (const float*)d_in[8];
  const float* Wo = (const float*)d_in[9];
  const float* bo = (const float*)d_in[10];

  const size_t NTOK = (size_t)B_ * S_ * D_;   // 4,194,304
  const size_t NW   = (size_t)D_ * D_;        // 1,048,576
  short* p = (short*)d_ws;
  short* qhi = p; p += NTOK;  short* qlo = p; p += NTOK;
  short* khi = p; p += NTOK;  short* klo = p; p += NTOK;
  short* vbf = p; p += NTOK;
  short* wqh = p; p += NW;    short* wql = p; p += NW;
  short* wkh = p; p += NW;    short* wkl = p; p += NW;
  short* wvb = p; p += NW;    short* wob = p; p += NW;
  short* Qhi = p; p += NTOK;  short* Qlo = p; p += NTOK;
  short* Khi = p; p += NTOK;  short* Klo = p; p += NTOK;
  short* Vt  = p; p += NTOK;  short* Ow  = p; p += NTOK;

  dim3 blk(256);
  const int gbig = (int)(NTOK / (256 * 8));   // 2048
  const int gsml = (int)(NW / (256 * 8));     // 512

  conv_split<<<gbig, blk, 0, stream>>>(q, qhi, qlo);
  conv_split<<<gbig, blk, 0, stream>>>(k, khi, klo);
  conv_split<<<gsml, blk, 0, stream>>>(Wq, wqh, wql);
  conv_split<<<gsml, blk, 0, stream>>>(Wk, wkh, wkl);
  conv_plain<<<gbig, blk, 0, stream>>>(v, vbf);
  conv_plain<<<gsml, blk, 0, stream>>>(Wv, wvb);
  conv_plain<<<gsml, blk, 0, stream>>>(Wo, wob);

  dim3 gg(D_ / 64, (B_ * S_) / 128);  // (16, 32)
  // scores in exp2 domain: fold 8*log2(e) into Q projection (incl. bias)
  const float QS = 11.541560327111707f;  // 8 * log2(e)
  gemm128<1, 1><<<gg, blk, 0, stream>>>(qhi, qlo, wqh, wql, bq, Qhi, Qlo, QS);
  gemm128<1, 1><<<gg, blk, 0, stream>>>(khi, klo, wkh, wkl, bk, Khi, Klo, 1.0f);
  gemm128<0, 2><<<gg, blk, 0, stream>>>(vbf, nullptr, wvb, nullptr, bv, Vt, nullptr, 1.0f);

  attn<<<dim3(S_ / 128, H_, B_), blk, 0, stream>>>(Qhi, Qlo, Khi, Klo, Vt, Ow);

  gemm128<0, 0><<<gg, blk, 0, stream>>>(Ow, nullptr, wob, nullptr, bo, d_out, nullptr, 1.0f);
}

// Round 4
// 367.655 us; speedup vs baseline: 1.3590x; 1.1347x over previous
//
#include <hip/hip_runtime.h>
#include <hip/hip_bf16.h>
#include <type_traits>
#include <utility>

#define B_ 2
#define S_ 2048
#define D_ 1024
#define H_ 16
#define HD_ 64
#define KDIM 1024

typedef __attribute__((ext_vector_type(8))) short   s16x8;
typedef __attribute__((ext_vector_type(8))) __bf16  b16x8;
typedef __attribute__((ext_vector_type(4))) float   f32x4;
typedef __attribute__((ext_vector_type(4))) int     i32x4;

// --- MFMA operand-type hedge ---
template <typename T, typename = void> struct mfma_takes : std::false_type {};
template <typename T>
struct mfma_takes<T, std::void_t<decltype(__builtin_amdgcn_mfma_f32_16x16x32_bf16(
    std::declval<T>(), std::declval<T>(), std::declval<f32x4>(), 0, 0, 0))>>
    : std::true_type {};
using frag8 = std::conditional_t<mfma_takes<s16x8>::value, s16x8, b16x8>;

__device__ __forceinline__ f32x4 mfma_bf16(frag8 a, frag8 b, f32x4 c) {
  return __builtin_amdgcn_mfma_f32_16x16x32_bf16(a, b, c, 0, 0, 0);
}

__device__ __forceinline__ short f2bf(float f) {  // RTNE f32 -> bf16 bits
  union { float f; unsigned u; } v; v.f = f;
  unsigned u = v.u;
  u += 0x7fffu + ((u >> 16) & 1u);
  return (short)(u >> 16);
}
__device__ __forceinline__ short f2bf_fast(float f) {  // ties-away, 2 VALU
  union { float f; unsigned u; } v; v.f = f;
  return (short)((v.u + 0x8000u) >> 16);
}
__device__ __forceinline__ void split_bf(float x, short& hi, short& lo) {
  const short h = f2bf(x);
  union { unsigned u; float f; } hv;
  hv.u = ((unsigned)(unsigned short)h) << 16;
  hi = h; lo = f2bf(x - hv.f);
}
__device__ __forceinline__ frag8 ld_frag(const short* p) {
  return __builtin_bit_cast(frag8, *(const i32x4*)p);
}

typedef __attribute__((address_space(1))) const void gvoid;
typedef __attribute__((address_space(3))) void lvoid;
__device__ __forceinline__ void async_copy16(const void* g, void* l) {
  __builtin_amdgcn_global_load_lds((gvoid*)g, (lvoid*)l, 16, 0, 0);
}

#define RAW_BARRIER() asm volatile("s_barrier" ::: "memory")
#define WAITCNT_VM(n) asm volatile("s_waitcnt vmcnt(" #n ")" ::: "memory")

// ---------------------------------------------------------------------------
// Fused elementwise converts: one launch for all 7 tensors.
// blocks: q 2048 | k 2048 | Wq 512 | Wk 512 | v 2048 | Wv 512 | Wo 512 = 8192
// ---------------------------------------------------------------------------
__global__ __launch_bounds__(256)
void conv_all(const float* __restrict__ q, const float* __restrict__ k,
              const float* __restrict__ v, const float* __restrict__ Wq,
              const float* __restrict__ Wk, const float* __restrict__ Wv,
              const float* __restrict__ Wo,
              short* __restrict__ qhi, short* __restrict__ qlo,
              short* __restrict__ khi, short* __restrict__ klo,
              short* __restrict__ wqh, short* __restrict__ wql,
              short* __restrict__ wkh, short* __restrict__ wkl,
              short* __restrict__ vbf, short* __restrict__ wvb,
              short* __restrict__ wob) {
  const int blk = blockIdx.x;
  const float* src; short* dhi; short* dlo; int split; int base;
  if (blk < 2048)      { src = q;  dhi = qhi; dlo = qlo; split = 1; base = blk; }
  else if (blk < 4096) { src = k;  dhi = khi; dlo = klo; split = 1; base = blk - 2048; }
  else if (blk < 4608) { src = Wq; dhi = wqh; dlo = wql; split = 1; base = blk - 4096; }
  else if (blk < 5120) { src = Wk; dhi = wkh; dlo = wkl; split = 1; base = blk - 4608; }
  else if (blk < 7168) { src = v;  dhi = vbf; dlo = nullptr; split = 0; base = blk - 5120; }
  else if (blk < 7680) { src = Wv; dhi = wvb; dlo = nullptr; split = 0; base = blk - 7168; }
  else                 { src = Wo; dhi = wob; dlo = nullptr; split = 0; base = blk - 7680; }
  const int i = base * 2048 + threadIdx.x * 8;
  float4 a0 = *(const float4*)(src + i);
  float4 a1 = *(const float4*)(src + i + 4);
  float xs[8] = { a0.x, a0.y, a0.z, a0.w, a1.x, a1.y, a1.z, a1.w };
  if (split) {
    short h[8], l[8];
#pragma unroll
    for (int j = 0; j < 8; ++j) split_bf(xs[j], h[j], l[j]);
    i32x4 ph, pl;
    __builtin_memcpy(&ph, h, 16); __builtin_memcpy(&pl, l, 16);
    *(i32x4*)(dhi + i) = ph; *(i32x4*)(dlo + i) = pl;
  } else {
    short h[8];
#pragma unroll
    for (int j = 0; j < 8; ++j) h[j] = f2bf(xs[j]);
    i32x4 ph; __builtin_memcpy(&ph, h, 16);
    *(i32x4*)(dhi + i) = ph;
  }
}

// ---------------------------------------------------------------------------
// bf16 NT GEMM, tile 128(M)x64(N), BK=32, DOUBLE-BUFFERED global_load_lds
// staging, raw s_barrier + fine-grained vmcnt (no full drain).
// XOR-swizzled LDS: LDS[row][g] holds global group g^((row>>1)&3).
// SPLIT: hi+lo planes, 3 MFMAs per product.
// OUT: 0 = fp32 flat [M,1024] (+bias); 1 = split bf16 planes [B,H,S,Hd]
// (scaled, +bias); 2 = bf16 Vt [B,H,Hd,S] (+bias).
// ---------------------------------------------------------------------------
template <int SPLIT, int OUT>
__global__ __launch_bounds__(256, 2)
void gemm_big(const short* __restrict__ Ahp, const short* __restrict__ Alp,
              const short* __restrict__ Bhp, const short* __restrict__ Blp,
              const float* __restrict__ bias, void* __restrict__ OutA,
              void* __restrict__ OutB, float scale) {
  __shared__ short AsH[2 * 4096];
  __shared__ short BsH[2 * 2048];
  __shared__ short AsL[SPLIT ? 2 * 4096 : 16];
  __shared__ short BsL[SPLIT ? 2 * 2048 : 16];

  const int t = threadIdx.x, wave = t >> 6, lane = t & 63;
  const int laneN = lane & 15, quad = lane >> 4;
  const int wm = wave & 1, wn = wave >> 1;
  const int bn = blockIdx.x, bm = blockIdx.y;

  f32x4 acc[4][2];
#pragma unroll
  for (int i = 0; i < 4; ++i)
#pragma unroll
    for (int j = 0; j < 2; ++j)
#pragma unroll
      for (int r = 0; r < 4; ++r) acc[i][j][r] = 0.f;

  auto stage = [&](int buf, int kk) {
#pragma unroll
    for (int j = 0; j < 2; ++j) {
      const int chunk = j * 256 + t;
      const int row = chunk >> 2;
      const int g = (chunk & 3) ^ ((row >> 1) & 3);
      const size_t ga = (size_t)(bm * 128 + row) * KDIM + kk + g * 8;
      async_copy16(Ahp + ga, AsH + buf * 4096 + chunk * 8);
      if (SPLIT) async_copy16(Alp + ga, AsL + buf * 4096 + chunk * 8);
    }
    {
      const int chunk = t;
      const int row = chunk >> 2;
      const int g = (chunk & 3) ^ ((row >> 1) & 3);
      const size_t gb = (size_t)(bn * 64 + row) * KDIM + kk + g * 8;
      async_copy16(Bhp + gb, BsH + buf * 2048 + chunk * 8);
      if (SPLIT) async_copy16(Blp + gb, BsL + buf * 2048 + chunk * 8);
    }
  };

  stage(0, 0);
  int buf = 0;
  for (int kk = 0; kk < KDIM; kk += 32, buf ^= 1) {
    if (kk + 32 < KDIM) stage(buf ^ 1, kk + 32);
    if (SPLIT) { WAITCNT_VM(6); } else { WAITCNT_VM(3); }
    RAW_BARRIER();

    frag8 aH[4], bH[2], aL[4], bL[2];
#pragma unroll
    for (int mi = 0; mi < 4; ++mi) {
      const int row = wm * 64 + mi * 16 + laneN;
      const int off = buf * 4096 + row * 32 + ((quad ^ ((row >> 1) & 3)) * 8);
      aH[mi] = ld_frag(AsH + off);
      if (SPLIT) aL[mi] = ld_frag(AsL + off);
    }
#pragma unroll
    for (int ni = 0; ni < 2; ++ni) {
      const int row = wn * 32 + ni * 16 + laneN;
      const int off = buf * 2048 + row * 32 + ((quad ^ ((row >> 1) & 3)) * 8);
      bH[ni] = ld_frag(BsH + off);
      if (SPLIT) bL[ni] = ld_frag(BsL + off);
    }
#pragma unroll
    for (int mi = 0; mi < 4; ++mi)
#pragma unroll
      for (int ni = 0; ni < 2; ++ni) {
        acc[mi][ni] = mfma_bf16(aH[mi], bH[ni], acc[mi][ni]);
        if (SPLIT) {
          acc[mi][ni] = mfma_bf16(aH[mi], bL[ni], acc[mi][ni]);
          acc[mi][ni] = mfma_bf16(aL[mi], bH[ni], acc[mi][ni]);
        }
      }
    RAW_BARRIER();  // all waves done reading buf before next stage overwrites
  }

  // Epilogue. C/D: col = lane&15, row = quad*4 + reg.
#pragma unroll
  for (int mi = 0; mi < 4; ++mi)
#pragma unroll
    for (int ni = 0; ni < 2; ++ni)
#pragma unroll
      for (int r = 0; r < 4; ++r) {
        const int rowg = bm * 128 + wm * 64 + mi * 16 + quad * 4 + r;
        const int colg = bn * 64 + wn * 32 + ni * 16 + laneN;
        float v = acc[mi][ni][r] + bias[colg];
        if (OUT == 0) {
          ((float*)OutA)[(size_t)rowg * 1024 + colg] = v;
        } else {
          const int b = rowg >> 11, s = rowg & 2047;
          const int h = colg >> 6, hd = colg & 63;
          if (OUT == 1) {
            v *= scale;
            const size_t idx = (((size_t)(b * H_ + h)) * S_ + s) * HD_ + hd;
            short hi, lo; split_bf(v, hi, lo);
            ((short*)OutA)[idx] = hi; ((short*)OutB)[idx] = lo;
          } else {  // Vt [B,H,Hd,S]
            const size_t idx = (((size_t)(b * H_ + h)) * HD_ + hd) * S_ + s;
            ((short*)OutA)[idx] = f2bf(v);
          }
        }
      }
}

// ---------------------------------------------------------------------------
// Flash attention: 128 q-rows/block, split QK^T, double-buffered async K/V
// staging (XOR swizzle g^(row&7)), Vt pre-transposed in global, exp2-domain
// softmax (Q pre-scaled 8*log2e). P strip reused across the two q-sets.
// LDS 57.3 KB -> 2 blocks/CU.
// ---------------------------------------------------------------------------
__global__ __launch_bounds__(256, 2)
void attn(const short* __restrict__ Qh_, const short* __restrict__ Ql_,
          const short* __restrict__ Kh_, const short* __restrict__ Kl_,
          const short* __restrict__ Vt_, short* __restrict__ Ow) {
  __shared__ short KsH[2 * 4096];
  __shared__ short KsL[2 * 4096];
  __shared__ short Vts[2 * 4096];
  __shared__ short Ps[4][16 * 72];  // per-wave P strip, reused across sets

  const int qt = blockIdx.x, h = blockIdx.y, b = blockIdx.z;
  const size_t head = ((size_t)b * H_ + h) * (size_t)S_ * HD_;

  const int t = threadIdx.x;
  const int wave = t >> 6, lane = t & 63;
  const int laneN = lane & 15, quad = lane >> 4;

  // Q frags direct from global
  frag8 qh[2][2], ql[2][2];
#pragma unroll
  for (int set = 0; set < 2; ++set) {
    const size_t row = (size_t)qt * 128 + wave * 32 + set * 16 + laneN;
#pragma unroll
    for (int half = 0; half < 2; ++half) {
      qh[set][half] = ld_frag(Qh_ + head + row * HD_ + half * 32 + quad * 8);
      ql[set][half] = ld_frag(Ql_ + head + row * HD_ + half * 32 + quad * 8);
    }
  }

  f32x4 o[2][4];
  float m_r[2][4], l_r[2][4];
#pragma unroll
  for (int st = 0; st < 2; ++st)
#pragma unroll
    for (int i = 0; i < 4; ++i) {
      m_r[st][i] = -1e30f; l_r[st][i] = 0.f;
#pragma unroll
      for (int j = 0; j < 4; ++j) o[st][i][j] = 0.f;
    }

  auto stage = [&](int buf, int kt) {
#pragma unroll
    for (int j = 0; j < 2; ++j) {
      const int chunk = j * 256 + t;
      const int row = chunk >> 3;
      const int g = (chunk & 7) ^ (row & 7);
      const int ldsoff = buf * 4096 + chunk * 8;
      async_copy16(Kh_ + head + (size_t)(kt * 64 + row) * HD_ + g * 8, KsH + ldsoff);
      async_copy16(Kl_ + head + (size_t)(kt * 64 + row) * HD_ + g * 8, KsL + ldsoff);
      async_copy16(Vt_ + head + (size_t)row * S_ + kt * 64 + g * 8, Vts + ldsoff);
    }
  };

  stage(0, 0);
  int buf = 0;
  for (int kt = 0; kt < 32; ++kt, buf ^= 1) {
    if (kt + 1 < 32) stage(buf ^ 1, kt + 1);
    WAITCNT_VM(6);
    RAW_BARRIER();

    // Vt frags (hoisted, each used by both q-sets)
    frag8 vf[4][2];
#pragma unroll
    for (int dt = 0; dt < 4; ++dt) {
      const int row = dt * 16 + laneN;
#pragma unroll
      for (int half = 0; half < 2; ++half)
        vf[dt][half] = ld_frag(Vts + buf * 4096 + row * 64 +
                               (((half * 4 + quad) ^ (row & 7)) * 8));
    }

    // scores
    f32x4 s[2][4];
#pragma unroll
    for (int nt = 0; nt < 4; ++nt) {
      const int row = nt * 16 + laneN;
      const int o0 = buf * 4096 + row * 64 + ((quad ^ (row & 7)) * 8);
      const int o1 = buf * 4096 + row * 64 + (((quad + 4) ^ (row & 7)) * 8);
      frag8 kh0 = ld_frag(KsH + o0), kh1 = ld_frag(KsH + o1);
      frag8 kl0 = ld_frag(KsL + o0), kl1 = ld_frag(KsL + o1);
#pragma unroll
      for (int st = 0; st < 2; ++st) {
        f32x4 acc;
#pragma unroll
        for (int j = 0; j < 4; ++j) acc[j] = 0.f;
        acc = mfma_bf16(qh[st][0], kh0, acc);
        acc = mfma_bf16(qh[st][0], kl0, acc);
        acc = mfma_bf16(ql[st][0], kh0, acc);
        acc = mfma_bf16(qh[st][1], kh1, acc);
        acc = mfma_bf16(qh[st][1], kl1, acc);
        acc = mfma_bf16(ql[st][1], kh1, acc);
        s[st][nt] = acc;
      }
    }

    // online softmax (exp2 domain)
#pragma unroll
    for (int st = 0; st < 2; ++st)
#pragma unroll
      for (int r = 0; r < 4; ++r) {
        float mx = fmaxf(fmaxf(s[st][0][r], s[st][1][r]),
                         fmaxf(s[st][2][r], s[st][3][r]));
        mx = fmaxf(mx, __shfl_xor(mx, 1));
        mx = fmaxf(mx, __shfl_xor(mx, 2));
        mx = fmaxf(mx, __shfl_xor(mx, 4));
        mx = fmaxf(mx, __shfl_xor(mx, 8));
        const float mn = fmaxf(m_r[st][r], mx);
        const float al = exp2f(m_r[st][r] - mn);
        m_r[st][r] = mn;
        float rs = 0.f;
#pragma unroll
        for (int nt = 0; nt < 4; ++nt) {
          const float p = exp2f(s[st][nt][r] - mn);
          s[st][nt][r] = p; rs += p;
        }
        rs += __shfl_xor(rs, 1);
        rs += __shfl_xor(rs, 2);
        rs += __shfl_xor(rs, 4);
        rs += __shfl_xor(rs, 8);
        l_r[st][r] = l_r[st][r] * al + rs;
#pragma unroll
        for (int dt = 0; dt < 4; ++dt) o[st][dt][r] *= al;
      }

    // P round-trip + PV, per set (strip reuse is safe: DS ops are in-order)
#pragma unroll
    for (int st = 0; st < 2; ++st) {
#pragma unroll
      for (int nt = 0; nt < 4; ++nt)
#pragma unroll
        for (int r = 0; r < 4; ++r)
          Ps[wave][(quad * 4 + r) * 72 + nt * 16 + laneN] = f2bf_fast(s[st][nt][r]);
      const frag8 p0 = ld_frag(&Ps[wave][laneN * 72 + quad * 8]);
      const frag8 p1 = ld_frag(&Ps[wave][laneN * 72 + 32 + quad * 8]);
#pragma unroll
      for (int dt = 0; dt < 4; ++dt) {
        o[st][dt] = mfma_bf16(p0, vf[dt][0], o[st][dt]);
        o[st][dt] = mfma_bf16(p1, vf[dt][1], o[st][dt]);
      }
    }
    RAW_BARRIER();  // all waves done with buf before next stage overwrites
  }

  // epilogue: O /= l, store bf16 [B,S,D]
#pragma unroll
  for (int st = 0; st < 2; ++st)
#pragma unroll
    for (int r = 0; r < 4; ++r) {
      const float inv = 1.0f / l_r[st][r];
      const int sg = qt * 128 + wave * 32 + st * 16 + quad * 4 + r;
#pragma unroll
      for (int dt = 0; dt < 4; ++dt) {
        const int d = dt * 16 + laneN;
        Ow[((size_t)b * S_ + sg) * D_ + h * HD_ + d] = f2bf(o[st][dt][r] * inv);
      }
    }
}

// ---------------------------------------------------------------------------
extern "C" void kernel_launch(void* const* d_in, const int* in_sizes, int n_in,
                              void* d_out, int out_size, void* d_ws, size_t ws_size,
                              hipStream_t stream) {
  const float* q  = (const float*)d_in[0];
  const float* k  = (const float*)d_in[1];
  const float* v  = (const float*)d_in[2];
  const float* Wq = (const float*)d_in[3];
  const float* bq = (const float*)d_in[4];
  const float* Wk = (const float*)d_in[5];
  const float* bk = (const float*)d_in[6];
  const float* Wv = (const float*)d_in[7];
  const float* bv = (const float*)d_in[8];
  const float* Wo = (const float*)d_in[9];
  const float* bo = (const float*)d_in[10];

  const size_t NTOK = (size_t)B_ * S_ * D_;   // 4,194,304
  const size_t NW   = (size_t)D_ * D_;        // 1,048,576
  short* p = (short*)d_ws;
  short* qhi = p; p += NTOK;  short* qlo = p; p += NTOK;
  short* khi = p; p += NTOK;  short* klo = p; p += NTOK;
  short* vbf = p; p += NTOK;
  short* wqh = p; p += NW;    short* wql = p; p += NW;
  short* wkh = p; p += NW;    short* wkl = p; p += NW;
  short* wvb = p; p += NW;    short* wob = p; p += NW;
  short* Qhi = p; p += NTOK;  short* Qlo = p; p += NTOK;
  short* Khi = p; p += NTOK;  short* Klo = p; p += NTOK;
  short* Vt  = p; p += NTOK;  short* Ow  = p; p += NTOK;

  dim3 blk(256);

  conv_all<<<8192, blk, 0, stream>>>(q, k, v, Wq, Wk, Wv, Wo,
                                     qhi, qlo, khi, klo, wqh, wql, wkh, wkl,
                                     vbf, wvb, wob);

  dim3 gg(D_ / 64, (B_ * S_) / 128);  // (16, 32) = 512 blocks
  const float QS = 11.541560327111707f;  // 8 * log2(e): exp2-domain softmax
  gemm_big<1, 1><<<gg, blk, 0, stream>>>(qhi, qlo, wqh, wql, bq, Qhi, Qlo, QS);
  gemm_big<1, 1><<<gg, blk, 0, stream>>>(khi, klo, wkh, wkl, bk, Khi, Klo, 1.0f);
  gemm_big<0, 2><<<gg, blk, 0, stream>>>(vbf, nullptr, wvb, nullptr, bv, Vt, nullptr, 1.0f);

  attn<<<dim3(S_ / 128, H_, B_), blk, 0, stream>>>(Qhi, Qlo, Khi, Klo, Vt, Ow);

  gemm_big<0, 0><<<gg, blk, 0, stream>>>(Ow, nullptr, wob, nullptr, bo, d_out, nullptr, 1.0f);
}

// Round 5
// 332.670 us; speedup vs baseline: 1.5019x; 1.1052x over previous
//
#include <hip/hip_runtime.h>
#include <hip/hip_bf16.h>
#include <type_traits>
#include <utility>

#define B_ 2
#define S_ 2048
#define D_ 1024
#define H_ 16
#define HD_ 64
#define KDIM 1024

typedef __attribute__((ext_vector_type(8))) short   s16x8;
typedef __attribute__((ext_vector_type(8))) __bf16  b16x8;
typedef __attribute__((ext_vector_type(4))) float   f32x4;
typedef __attribute__((ext_vector_type(4))) int     i32x4;
typedef __attribute__((ext_vector_type(2))) int     i32x2;

// --- MFMA operand-type hedge ---
template <typename T, typename = void> struct mfma_takes : std::false_type {};
template <typename T>
struct mfma_takes<T, std::void_t<decltype(__builtin_amdgcn_mfma_f32_16x16x32_bf16(
    std::declval<T>(), std::declval<T>(), std::declval<f32x4>(), 0, 0, 0))>>
    : std::true_type {};
using frag8 = std::conditional_t<mfma_takes<s16x8>::value, s16x8, b16x8>;

__device__ __forceinline__ f32x4 mfma_bf16(frag8 a, frag8 b, f32x4 c) {
  return __builtin_amdgcn_mfma_f32_16x16x32_bf16(a, b, c, 0, 0, 0);
}

__device__ __forceinline__ short f2bf(float f) {  // RTNE f32 -> bf16 bits
  union { float f; unsigned u; } v; v.f = f;
  unsigned u = v.u;
  u += 0x7fffu + ((u >> 16) & 1u);
  return (short)(u >> 16);
}
__device__ __forceinline__ short f2bf_fast(float f) {  // ties-away, 2 VALU
  union { float f; unsigned u; } v; v.f = f;
  return (short)((v.u + 0x8000u) >> 16);
}
__device__ __forceinline__ void split_bf(float x, short& hi, short& lo) {
  const short h = f2bf(x);
  union { unsigned u; float f; } hv;
  hv.u = ((unsigned)(unsigned short)h) << 16;
  hi = h; lo = f2bf(x - hv.f);
}
__device__ __forceinline__ frag8 ld_frag(const short* p) {
  return __builtin_bit_cast(frag8, *(const i32x4*)p);
}

typedef __attribute__((address_space(1))) const void gvoid;
typedef __attribute__((address_space(3))) void lvoid;
__device__ __forceinline__ void async_copy16(const void* g, void* l) {
  __builtin_amdgcn_global_load_lds((gvoid*)g, (lvoid*)l, 16, 0, 0);
}

#define RAW_BARRIER() asm volatile("s_barrier" ::: "memory")
#define WAITCNT_VM(n) asm volatile("s_waitcnt vmcnt(" #n ")" ::: "memory")

// ---------------------------------------------------------------------------
// Fused elementwise converts: one launch for all 7 tensors.
// ---------------------------------------------------------------------------
__global__ __launch_bounds__(256)
void conv_all(const float* __restrict__ q, const float* __restrict__ k,
              const float* __restrict__ v, const float* __restrict__ Wq,
              const float* __restrict__ Wk, const float* __restrict__ Wv,
              const float* __restrict__ Wo,
              short* __restrict__ qhi, short* __restrict__ qlo,
              short* __restrict__ khi, short* __restrict__ klo,
              short* __restrict__ wqh, short* __restrict__ wql,
              short* __restrict__ wkh, short* __restrict__ wkl,
              short* __restrict__ vbf, short* __restrict__ wvb,
              short* __restrict__ wob) {
  const int blk = blockIdx.x;
  const float* src; short* dhi; short* dlo; int split; int base;
  if (blk < 2048)      { src = q;  dhi = qhi; dlo = qlo; split = 1; base = blk; }
  else if (blk < 4096) { src = k;  dhi = khi; dlo = klo; split = 1; base = blk - 2048; }
  else if (blk < 4608) { src = Wq; dhi = wqh; dlo = wql; split = 1; base = blk - 4096; }
  else if (blk < 5120) { src = Wk; dhi = wkh; dlo = wkl; split = 1; base = blk - 4608; }
  else if (blk < 7168) { src = v;  dhi = vbf; dlo = nullptr; split = 0; base = blk - 5120; }
  else if (blk < 7680) { src = Wv; dhi = wvb; dlo = nullptr; split = 0; base = blk - 7168; }
  else                 { src = Wo; dhi = wob; dlo = nullptr; split = 0; base = blk - 7680; }
  const int i = base * 2048 + threadIdx.x * 8;
  float4 a0 = *(const float4*)(src + i);
  float4 a1 = *(const float4*)(src + i + 4);
  float xs[8] = { a0.x, a0.y, a0.z, a0.w, a1.x, a1.y, a1.z, a1.w };
  if (split) {
    short h[8], l[8];
#pragma unroll
    for (int j = 0; j < 8; ++j) split_bf(xs[j], h[j], l[j]);
    i32x4 ph, pl;
    __builtin_memcpy(&ph, h, 16); __builtin_memcpy(&pl, l, 16);
    *(i32x4*)(dhi + i) = ph; *(i32x4*)(dlo + i) = pl;
  } else {
    short h[8];
#pragma unroll
    for (int j = 0; j < 8; ++j) h[j] = f2bf(xs[j]);
    i32x4 ph; __builtin_memcpy(&ph, h, 16);
    *(i32x4*)(dhi + i) = ph;
  }
}

// ---------------------------------------------------------------------------
// Shared GEMM body: tile 128(M)x64(N), BK=32, double-buffered global_load_lds,
// raw s_barrier + fine vmcnt. XOR-swizzled LDS.
// ---------------------------------------------------------------------------
template <int SPLIT, int OUT>
__device__ __forceinline__
void gemm_body(const short* __restrict__ Ahp, const short* __restrict__ Alp,
               const short* __restrict__ Bhp, const short* __restrict__ Blp,
               const float* __restrict__ bias, void* __restrict__ OutA,
               void* __restrict__ OutB, float scale, short* AsH, short* BsH,
               short* AsL, short* BsL, int bm, int bn) {
  const int t = threadIdx.x, wave = t >> 6, lane = t & 63;
  const int laneN = lane & 15, quad = lane >> 4;
  const int wm = wave & 1, wn = wave >> 1;

  f32x4 acc[4][2];
#pragma unroll
  for (int i = 0; i < 4; ++i)
#pragma unroll
    for (int j = 0; j < 2; ++j)
#pragma unroll
      for (int r = 0; r < 4; ++r) acc[i][j][r] = 0.f;

  auto stage = [&](int buf, int kk) {
#pragma unroll
    for (int j = 0; j < 2; ++j) {
      const int chunk = j * 256 + t;
      const int row = chunk >> 2;
      const int g = (chunk & 3) ^ ((row >> 1) & 3);
      const size_t ga = (size_t)(bm * 128 + row) * KDIM + kk + g * 8;
      async_copy16(Ahp + ga, AsH + buf * 4096 + chunk * 8);
      if (SPLIT) async_copy16(Alp + ga, AsL + buf * 4096 + chunk * 8);
    }
    {
      const int chunk = t;
      const int row = chunk >> 2;
      const int g = (chunk & 3) ^ ((row >> 1) & 3);
      const size_t gb = (size_t)(bn * 64 + row) * KDIM + kk + g * 8;
      async_copy16(Bhp + gb, BsH + buf * 2048 + chunk * 8);
      if (SPLIT) async_copy16(Blp + gb, BsL + buf * 2048 + chunk * 8);
    }
  };

  stage(0, 0);
  int buf = 0;
  for (int kk = 0; kk < KDIM; kk += 32, buf ^= 1) {
    if (kk + 32 < KDIM) stage(buf ^ 1, kk + 32);
    if (SPLIT) { WAITCNT_VM(6); } else { WAITCNT_VM(3); }
    RAW_BARRIER();

    frag8 aH[4], bH[2], aL[4], bL[2];
#pragma unroll
    for (int mi = 0; mi < 4; ++mi) {
      const int row = wm * 64 + mi * 16 + laneN;
      const int off = buf * 4096 + row * 32 + ((quad ^ ((row >> 1) & 3)) * 8);
      aH[mi] = ld_frag(AsH + off);
      if (SPLIT) aL[mi] = ld_frag(AsL + off);
    }
#pragma unroll
    for (int ni = 0; ni < 2; ++ni) {
      const int row = wn * 32 + ni * 16 + laneN;
      const int off = buf * 2048 + row * 32 + ((quad ^ ((row >> 1) & 3)) * 8);
      bH[ni] = ld_frag(BsH + off);
      if (SPLIT) bL[ni] = ld_frag(BsL + off);
    }
#pragma unroll
    for (int mi = 0; mi < 4; ++mi)
#pragma unroll
      for (int ni = 0; ni < 2; ++ni) {
        acc[mi][ni] = mfma_bf16(aH[mi], bH[ni], acc[mi][ni]);
        if (SPLIT) {
          acc[mi][ni] = mfma_bf16(aH[mi], bL[ni], acc[mi][ni]);
          acc[mi][ni] = mfma_bf16(aL[mi], bH[ni], acc[mi][ni]);
        }
      }
    RAW_BARRIER();
  }

#pragma unroll
  for (int mi = 0; mi < 4; ++mi)
#pragma unroll
    for (int ni = 0; ni < 2; ++ni)
#pragma unroll
      for (int r = 0; r < 4; ++r) {
        const int rowg = bm * 128 + wm * 64 + mi * 16 + quad * 4 + r;
        const int colg = bn * 64 + wn * 32 + ni * 16 + laneN;
        float v = acc[mi][ni][r] + bias[colg];
        if (OUT == 0) {
          ((float*)OutA)[(size_t)rowg * 1024 + colg] = v;
        } else {
          const int b = rowg >> 11, s = rowg & 2047;
          const int h = colg >> 6, hd = colg & 63;
          if (OUT == 1) {
            v *= scale;
            const size_t idx = (((size_t)(b * H_ + h)) * S_ + s) * HD_ + hd;
            short hi, lo; split_bf(v, hi, lo);
            ((short*)OutA)[idx] = hi; ((short*)OutB)[idx] = lo;
          } else {  // Vt [B,H,Hd,S]
            const size_t idx = (((size_t)(b * H_ + h)) * HD_ + hd) * S_ + s;
            ((short*)OutA)[idx] = f2bf(v);
          }
        }
      }
}

template <int SPLIT, int OUT>
__global__ __launch_bounds__(256, 2)
void gemm_big(const short* __restrict__ Ahp, const short* __restrict__ Alp,
              const short* __restrict__ Bhp, const short* __restrict__ Blp,
              const float* __restrict__ bias, void* __restrict__ OutA,
              void* __restrict__ OutB, float scale) {
  __shared__ short AsH[2 * 4096];
  __shared__ short BsH[2 * 2048];
  __shared__ short AsL[SPLIT ? 2 * 4096 : 16];
  __shared__ short BsL[SPLIT ? 2 * 2048 : 16];
  gemm_body<SPLIT, OUT>(Ahp, Alp, Bhp, Blp, bias, OutA, OutB, scale,
                        AsH, BsH, AsL, BsL, blockIdx.y, blockIdx.x);
}

// Fused Q+K split projections: blockIdx.z selects tensor set.
__global__ __launch_bounds__(256, 2)
void gemm_qk(const short* __restrict__ qhi, const short* __restrict__ qlo,
             const short* __restrict__ khi, const short* __restrict__ klo,
             const short* __restrict__ wqh, const short* __restrict__ wql,
             const short* __restrict__ wkh, const short* __restrict__ wkl,
             const float* __restrict__ bq, const float* __restrict__ bk,
             short* __restrict__ Qhi, short* __restrict__ Qlo,
             short* __restrict__ Khi, short* __restrict__ Klo, float QS) {
  __shared__ short AsH[2 * 4096];
  __shared__ short BsH[2 * 2048];
  __shared__ short AsL[2 * 4096];
  __shared__ short BsL[2 * 2048];
  const int z = blockIdx.z;
  gemm_body<1, 1>(z ? khi : qhi, z ? klo : qlo, z ? wkh : wqh, z ? wkl : wql,
                  z ? bk : bq, z ? (void*)Khi : (void*)Qhi,
                  z ? (void*)Klo : (void*)Qlo, z ? 1.0f : QS,
                  AsH, BsH, AsL, BsL, blockIdx.y, blockIdx.x);
}

// ---------------------------------------------------------------------------
// Flash attention, TRANSPOSED scores: mfma(A=K, B=Q) -> S^T (row=k quad*4+r,
// col=q laneN). Softmax per q is in-lane (16 regs) + 2 quad-shuffles.
// P pack: 4 consecutive k per nt -> ds_write_b64. PV: mfma(A=Vt, B=P) -> O^T.
// Double-buffered async K/V staging, exp2-domain softmax (Q pre-scaled
// 8*log2e). LDS 58.4 KB -> 2 blocks/CU.
// ---------------------------------------------------------------------------
__global__ __launch_bounds__(256, 2)
void attn(const short* __restrict__ Qh_, const short* __restrict__ Ql_,
          const short* __restrict__ Kh_, const short* __restrict__ Kl_,
          const short* __restrict__ Vt_, short* __restrict__ Ow) {
  __shared__ short KsH[2 * 4096];
  __shared__ short KsL[2 * 4096];
  __shared__ short Vts[2 * 4096];
  __shared__ short Ps[4][16 * 72];  // per-wave P strip [q][k], reused per set

  const int qt = blockIdx.x, h = blockIdx.y, b = blockIdx.z;
  const size_t head = ((size_t)b * H_ + h) * (size_t)S_ * HD_;

  const int t = threadIdx.x;
  const int wave = t >> 6, lane = t & 63;
  const int laneN = lane & 15, quad = lane >> 4;

  // Q frags direct from global (B-operand layout == A-operand layout)
  frag8 qh[2][2], ql[2][2];
#pragma unroll
  for (int set = 0; set < 2; ++set) {
    const size_t row = (size_t)qt * 128 + wave * 32 + set * 16 + laneN;
#pragma unroll
    for (int half = 0; half < 2; ++half) {
      qh[set][half] = ld_frag(Qh_ + head + row * HD_ + half * 32 + quad * 8);
      ql[set][half] = ld_frag(Ql_ + head + row * HD_ + half * 32 + quad * 8);
    }
  }

  f32x4 o[2][4];          // O^T: row d = dt*16+quad*4+r, col q = laneN
  float m_r[2], l_r[2];   // per-lane scalars (lane owns q = laneN per set)
#pragma unroll
  for (int st = 0; st < 2; ++st) {
    m_r[st] = -1e30f; l_r[st] = 0.f;
#pragma unroll
    for (int i = 0; i < 4; ++i)
#pragma unroll
      for (int j = 0; j < 4; ++j) o[st][i][j] = 0.f;
  }

  auto stage = [&](int buf, int kt) {
#pragma unroll
    for (int j = 0; j < 2; ++j) {
      const int chunk = j * 256 + t;
      const int row = chunk >> 3;
      const int g = (chunk & 7) ^ (row & 7);
      const int ldsoff = buf * 4096 + chunk * 8;
      async_copy16(Kh_ + head + (size_t)(kt * 64 + row) * HD_ + g * 8, KsH + ldsoff);
      async_copy16(Kl_ + head + (size_t)(kt * 64 + row) * HD_ + g * 8, KsL + ldsoff);
      async_copy16(Vt_ + head + (size_t)row * S_ + kt * 64 + g * 8, Vts + ldsoff);
    }
  };

  stage(0, 0);
  int buf = 0;
  for (int kt = 0; kt < 32; ++kt, buf ^= 1) {
    if (kt + 1 < 32) stage(buf ^ 1, kt + 1);
    WAITCNT_VM(6);
    RAW_BARRIER();

    // Vt frags (A-operand of PV): rows d = dt*16+laneN
    frag8 vf[4][2];
#pragma unroll
    for (int dt = 0; dt < 4; ++dt) {
      const int row = dt * 16 + laneN;
#pragma unroll
      for (int half = 0; half < 2; ++half)
        vf[dt][half] = ld_frag(Vts + buf * 4096 + row * 64 +
                               (((half * 4 + quad) ^ (row & 7)) * 8));
    }

    // S^T = K·Q^T: per lane 16 logits for q=laneN, k = nt*16+quad*4+r
    f32x4 s[2][4];
#pragma unroll
    for (int nt = 0; nt < 4; ++nt) {
      const int row = nt * 16 + laneN;
      const int o0 = buf * 4096 + row * 64 + ((quad ^ (row & 7)) * 8);
      const int o1 = buf * 4096 + row * 64 + (((quad + 4) ^ (row & 7)) * 8);
      frag8 kh0 = ld_frag(KsH + o0), kh1 = ld_frag(KsH + o1);
      frag8 kl0 = ld_frag(KsL + o0), kl1 = ld_frag(KsL + o1);
#pragma unroll
      for (int st = 0; st < 2; ++st) {
        f32x4 acc;
#pragma unroll
        for (int j = 0; j < 4; ++j) acc[j] = 0.f;
        acc = mfma_bf16(kh0, qh[st][0], acc);
        acc = mfma_bf16(kl0, qh[st][0], acc);
        acc = mfma_bf16(kh0, ql[st][0], acc);
        acc = mfma_bf16(kh1, qh[st][1], acc);
        acc = mfma_bf16(kl1, qh[st][1], acc);
        acc = mfma_bf16(kh1, ql[st][1], acc);
        s[st][nt] = acc;
      }
    }

    // online softmax per set: in-lane reduce over 16 regs + 2 quad shuffles
#pragma unroll
    for (int st = 0; st < 2; ++st) {
      float mx = -1e30f;
#pragma unroll
      for (int nt = 0; nt < 4; ++nt)
#pragma unroll
        for (int r = 0; r < 4; ++r) mx = fmaxf(mx, s[st][nt][r]);
      mx = fmaxf(mx, __shfl_xor(mx, 16));
      mx = fmaxf(mx, __shfl_xor(mx, 32));
      const float mn = fmaxf(m_r[st], mx);
      const float al = exp2f(m_r[st] - mn);
      m_r[st] = mn;
      float rs = 0.f;
#pragma unroll
      for (int nt = 0; nt < 4; ++nt)
#pragma unroll
        for (int r = 0; r < 4; ++r) {
          const float p = exp2f(s[st][nt][r] - mn);
          s[st][nt][r] = p; rs += p;
        }
      rs += __shfl_xor(rs, 16);
      rs += __shfl_xor(rs, 32);
      l_r[st] = l_r[st] * al + rs;
#pragma unroll
      for (int dt = 0; dt < 4; ++dt)
#pragma unroll
        for (int r = 0; r < 4; ++r) o[st][dt][r] *= al;

      // P pack: 4 consecutive k per nt -> one b64 LDS write; strip [q][k]
#pragma unroll
      for (int nt = 0; nt < 4; ++nt) {
        short pk[4] = { f2bf_fast(s[st][nt][0]), f2bf_fast(s[st][nt][1]),
                        f2bf_fast(s[st][nt][2]), f2bf_fast(s[st][nt][3]) };
        i32x2 w; __builtin_memcpy(&w, pk, 8);
        *(i32x2*)&Ps[wave][laneN * 72 + nt * 16 + quad * 4] = w;
      }
      // B-operand P frags: [q=laneN][k=half*32+quad*8 ..]
      const frag8 p0 = ld_frag(&Ps[wave][laneN * 72 + quad * 8]);
      const frag8 p1 = ld_frag(&Ps[wave][laneN * 72 + 32 + quad * 8]);
#pragma unroll
      for (int dt = 0; dt < 4; ++dt) {
        o[st][dt] = mfma_bf16(vf[dt][0], p0, o[st][dt]);
        o[st][dt] = mfma_bf16(vf[dt][1], p1, o[st][dt]);
      }
    }
    RAW_BARRIER();
  }

  // epilogue: O^T -> Ow[B,S,D]; lane owns q, 4 consecutive d per (st,dt)
#pragma unroll
  for (int st = 0; st < 2; ++st) {
    const float inv = 1.0f / l_r[st];
    const int sg = qt * 128 + wave * 32 + st * 16 + laneN;
    short* dst = Ow + ((size_t)b * S_ + sg) * D_ + h * HD_;
#pragma unroll
    for (int dt = 0; dt < 4; ++dt) {
      short pk[4] = { f2bf(o[st][dt][0] * inv), f2bf(o[st][dt][1] * inv),
                      f2bf(o[st][dt][2] * inv), f2bf(o[st][dt][3] * inv) };
      i32x2 w; __builtin_memcpy(&w, pk, 8);
      *(i32x2*)(dst + dt * 16 + quad * 4) = w;
    }
  }
}

// ---------------------------------------------------------------------------
extern "C" void kernel_launch(void* const* d_in, const int* in_sizes, int n_in,
                              void* d_out, int out_size, void* d_ws, size_t ws_size,
                              hipStream_t stream) {
  const float* q  = (const float*)d_in[0];
  const float* k  = (const float*)d_in[1];
  const float* v  = (const float*)d_in[2];
  const float* Wq = (const float*)d_in[3];
  const float* bq = (const float*)d_in[4];
  const float* Wk = (const float*)d_in[5];
  const float* bk = (const float*)d_in[6];
  const float* Wv = (const float*)d_in[7];
  const float* bv = (const float*)d_in[8];
  const float* Wo = (const float*)d_in[9];
  const float* bo = (const float*)d_in[10];

  const size_t NTOK = (size_t)B_ * S_ * D_;   // 4,194,304
  const size_t NW   = (size_t)D_ * D_;        // 1,048,576
  short* p = (short*)d_ws;
  short* qhi = p; p += NTOK;  short* qlo = p; p += NTOK;
  short* khi = p; p += NTOK;  short* klo = p; p += NTOK;
  short* vbf = p; p += NTOK;
  short* wqh = p; p += NW;    short* wql = p; p += NW;
  short* wkh = p; p += NW;    short* wkl = p; p += NW;
  short* wvb = p; p += NW;    short* wob = p; p += NW;
  short* Qhi = p; p += NTOK;  short* Qlo = p; p += NTOK;
  short* Khi = p; p += NTOK;  short* Klo = p; p += NTOK;
  short* Vt  = p; p += NTOK;  short* Ow  = p; p += NTOK;

  dim3 blk(256);

  conv_all<<<8192, blk, 0, stream>>>(q, k, v, Wq, Wk, Wv, Wo,
                                     qhi, qlo, khi, klo, wqh, wql, wkh, wkl,
                                     vbf, wvb, wob);

  const float QS = 11.541560327111707f;  // 8 * log2(e): exp2-domain softmax
  dim3 gqk(D_ / 64, (B_ * S_) / 128, 2);  // (16, 32, 2) = 1024 blocks
  gemm_qk<<<gqk, blk, 0, stream>>>(qhi, qlo, khi, klo, wqh, wql, wkh, wkl,
                                   bq, bk, Qhi, Qlo, Khi, Klo, QS);

  dim3 gg(D_ / 64, (B_ * S_) / 128);  // (16, 32) = 512 blocks
  gemm_big<0, 2><<<gg, blk, 0, stream>>>(vbf, nullptr, wvb, nullptr, bv, Vt, nullptr, 1.0f);

  attn<<<dim3(S_ / 128, H_, B_), blk, 0, stream>>>(Qhi, Qlo, Khi, Klo, Vt, Ow);

  gemm_big<0, 0><<<gg, blk, 0, stream>>>(Ow, nullptr, wob, nullptr, bo, d_out, nullptr, 1.0f);
}

// Round 6
// 283.263 us; speedup vs baseline: 1.7639x; 1.1744x over previous
//
#include <hip/hip_runtime.h>
#include <type_traits>
#include <utility>

#define B_ 2
#define S_ 2048
#define D_ 1024
#define H_ 16
#define HD_ 64
#define KDIM 1024

typedef __attribute__((ext_vector_type(8))) short    s16x8;
typedef __attribute__((ext_vector_type(8))) _Float16 h16x8;
typedef __attribute__((ext_vector_type(4))) float    f32x4;
typedef __attribute__((ext_vector_type(4))) int      i32x4;
typedef __attribute__((ext_vector_type(2))) int      i32x2;

// --- MFMA operand-type hedge (fp16) ---
template <typename T, typename = void> struct mfma_takes : std::false_type {};
template <typename T>
struct mfma_takes<T, std::void_t<decltype(__builtin_amdgcn_mfma_f32_16x16x32_f16(
    std::declval<T>(), std::declval<T>(), std::declval<f32x4>(), 0, 0, 0))>>
    : std::true_type {};
using frag8 = std::conditional_t<mfma_takes<h16x8>::value, h16x8, s16x8>;

__device__ __forceinline__ f32x4 mfma_f16(frag8 a, frag8 b, f32x4 c) {
  return __builtin_amdgcn_mfma_f32_16x16x32_f16(a, b, c, 0, 0, 0);
}

__device__ __forceinline__ short f2h(float f) {  // RTNE f32 -> fp16 bits
  _Float16 h = (_Float16)f;
  short s; __builtin_memcpy(&s, &h, 2);
  return s;
}
__device__ __forceinline__ frag8 ld_frag(const short* p) {
  return __builtin_bit_cast(frag8, *(const i32x4*)p);
}

typedef __attribute__((address_space(1))) const void gvoid;
typedef __attribute__((address_space(3))) void lvoid;
__device__ __forceinline__ void async_copy16(const void* g, void* l) {
  __builtin_amdgcn_global_load_lds((gvoid*)g, (lvoid*)l, 16, 0, 0);
}

#define RAW_BARRIER() asm volatile("s_barrier" ::: "memory")
#define WAITCNT_VM(n) asm volatile("s_waitcnt vmcnt(" #n ")" ::: "memory")

// ---------------------------------------------------------------------------
// Fused fp32 -> fp16 converts, one launch for all 7 tensors.
// blocks: q 2048 | k 2048 | v 2048 | Wq 512 | Wk 512 | Wv 512 | Wo 512 = 8192
// ---------------------------------------------------------------------------
__global__ __launch_bounds__(256)
void conv_all(const float* __restrict__ q, const float* __restrict__ k,
              const float* __restrict__ v, const float* __restrict__ Wq,
              const float* __restrict__ Wk, const float* __restrict__ Wv,
              const float* __restrict__ Wo,
              short* __restrict__ qh, short* __restrict__ kh,
              short* __restrict__ vh, short* __restrict__ wq,
              short* __restrict__ wk, short* __restrict__ wv,
              short* __restrict__ wo) {
  const int blk = blockIdx.x;
  const float* src; short* dst; int base;
  if (blk < 2048)      { src = q;  dst = qh; base = blk; }
  else if (blk < 4096) { src = k;  dst = kh; base = blk - 2048; }
  else if (blk < 6144) { src = v;  dst = vh; base = blk - 4096; }
  else if (blk < 6656) { src = Wq; dst = wq; base = blk - 6144; }
  else if (blk < 7168) { src = Wk; dst = wk; base = blk - 6656; }
  else if (blk < 7680) { src = Wv; dst = wv; base = blk - 7168; }
  else                 { src = Wo; dst = wo; base = blk - 7680; }
  const int i = base * 2048 + threadIdx.x * 8;
  float4 a0 = *(const float4*)(src + i);
  float4 a1 = *(const float4*)(src + i + 4);
  short h[8] = { f2h(a0.x), f2h(a0.y), f2h(a0.z), f2h(a0.w),
                 f2h(a1.x), f2h(a1.y), f2h(a1.z), f2h(a1.w) };
  i32x4 ph; __builtin_memcpy(&ph, h, 16);
  *(i32x4*)(dst + i) = ph;
}

// ---------------------------------------------------------------------------
// fp16 NT GEMM body: tile 128(M)x64(N), BK=32, double-buffered
// global_load_lds, raw s_barrier + fine vmcnt, XOR-swizzled LDS.
// OUTK 0: fp32 flat [M,1024] (+bias).
// OUTK 1: fp16; omode 1 -> [B,H,S,Hd] (scaled, +bias); omode 2 -> Vt [B,H,Hd,S].
// ---------------------------------------------------------------------------
template <int OUTK>
__device__ __forceinline__
void gemm_body(const short* __restrict__ Ap, const short* __restrict__ Wp,
               const float* __restrict__ bias, void* __restrict__ Out,
               float scale, int omode, short* As, short* Bs, int bm, int bn) {
  const int t = threadIdx.x, wave = t >> 6, lane = t & 63;
  const int laneN = lane & 15, quad = lane >> 4;
  const int wm = wave & 1, wn = wave >> 1;

  f32x4 acc[4][2];
#pragma unroll
  for (int i = 0; i < 4; ++i)
#pragma unroll
    for (int j = 0; j < 2; ++j)
#pragma unroll
      for (int r = 0; r < 4; ++r) acc[i][j][r] = 0.f;

  auto stage = [&](int buf, int kk) {
#pragma unroll
    for (int j = 0; j < 2; ++j) {
      const int chunk = j * 256 + t;
      const int row = chunk >> 2;
      const int g = (chunk & 3) ^ ((row >> 1) & 3);
      async_copy16(Ap + (size_t)(bm * 128 + row) * KDIM + kk + g * 8,
                   As + buf * 4096 + chunk * 8);
    }
    {
      const int chunk = t;
      const int row = chunk >> 2;
      const int g = (chunk & 3) ^ ((row >> 1) & 3);
      async_copy16(Wp + (size_t)(bn * 64 + row) * KDIM + kk + g * 8,
                   Bs + buf * 2048 + chunk * 8);
    }
  };

  stage(0, 0);
  int buf = 0;
  for (int kk = 0; kk < KDIM; kk += 32, buf ^= 1) {
    if (kk + 32 < KDIM) stage(buf ^ 1, kk + 32);
    WAITCNT_VM(3);
    RAW_BARRIER();

    frag8 aF[4], bF[2];
#pragma unroll
    for (int mi = 0; mi < 4; ++mi) {
      const int row = wm * 64 + mi * 16 + laneN;
      aF[mi] = ld_frag(As + buf * 4096 + row * 32 +
                       ((quad ^ ((row >> 1) & 3)) * 8));
    }
#pragma unroll
    for (int ni = 0; ni < 2; ++ni) {
      const int row = wn * 32 + ni * 16 + laneN;
      bF[ni] = ld_frag(Bs + buf * 2048 + row * 32 +
                       ((quad ^ ((row >> 1) & 3)) * 8));
    }
#pragma unroll
    for (int mi = 0; mi < 4; ++mi)
#pragma unroll
      for (int ni = 0; ni < 2; ++ni)
        acc[mi][ni] = mfma_f16(aF[mi], bF[ni], acc[mi][ni]);
    RAW_BARRIER();
  }

  // Epilogue. C/D: col = lane&15, row = quad*4 + reg.
#pragma unroll
  for (int mi = 0; mi < 4; ++mi)
#pragma unroll
    for (int ni = 0; ni < 2; ++ni)
#pragma unroll
      for (int r = 0; r < 4; ++r) {
        const int rowg = bm * 128 + wm * 64 + mi * 16 + quad * 4 + r;
        const int colg = bn * 64 + wn * 32 + ni * 16 + laneN;
        const float v = acc[mi][ni][r] + bias[colg];
        if (OUTK == 0) {
          ((float*)Out)[(size_t)rowg * 1024 + colg] = v;
        } else {
          const int b = rowg >> 11, s = rowg & 2047;
          const int h = colg >> 6, hd = colg & 63;
          if (omode == 1) {
            ((short*)Out)[(((size_t)(b * H_ + h)) * S_ + s) * HD_ + hd] =
                f2h(v * scale);
          } else {  // Vt [B,H,Hd,S]
            ((short*)Out)[(((size_t)(b * H_ + h)) * HD_ + hd) * S_ + s] = f2h(v);
          }
        }
      }
}

// Fused Q+K+V projections: blockIdx.z selects tensor.
__global__ __launch_bounds__(256, 4)
void gemm_qkv(const short* __restrict__ qh, const short* __restrict__ kh,
              const short* __restrict__ vh, const short* __restrict__ wq,
              const short* __restrict__ wk, const short* __restrict__ wv,
              const float* __restrict__ bq, const float* __restrict__ bk,
              const float* __restrict__ bv, short* __restrict__ Qf,
              short* __restrict__ Kf, short* __restrict__ Vt, float QS) {
  __shared__ short As[2 * 4096];
  __shared__ short Bs[2 * 2048];
  const int z = blockIdx.z;
  const short* A = z == 0 ? qh : z == 1 ? kh : vh;
  const short* W = z == 0 ? wq : z == 1 ? wk : wv;
  const float* bias = z == 0 ? bq : z == 1 ? bk : bv;
  short* Out = z == 0 ? Qf : z == 1 ? Kf : Vt;
  gemm_body<1>(A, W, bias, Out, z == 0 ? QS : 1.0f, z == 2 ? 2 : 1,
               As, Bs, blockIdx.y, blockIdx.x);
}

// O projection: fp16 A x fp16 W -> fp32 out.
__global__ __launch_bounds__(256, 4)
void gemm_out(const short* __restrict__ Ow, const short* __restrict__ wo,
              const float* __restrict__ bo, float* __restrict__ out) {
  __shared__ short As[2 * 4096];
  __shared__ short Bs[2 * 2048];
  gemm_body<0>(Ow, wo, bo, out, 1.0f, 0, As, Bs, blockIdx.y, blockIdx.x);
}

// ---------------------------------------------------------------------------
// Flash attention, fp16, transposed scores: mfma(A=K, B=Q) -> S^T
// (row = k local, col = q = laneN). In-lane softmax (16 regs) + 2 shuffles.
// PV: mfma(A=Vt, B=P) -> O^T. Double-buffered async K/V staging, exp2-domain
// softmax (Q pre-scaled 8*log2e). LDS 41.2 KB -> 3 blocks/CU.
// ---------------------------------------------------------------------------
__global__ __launch_bounds__(256, 3)
void attn(const short* __restrict__ Qf, const short* __restrict__ Kf,
          const short* __restrict__ Vt_, short* __restrict__ Ow) {
  __shared__ short Ks[2 * 4096];
  __shared__ short Vts[2 * 4096];
  __shared__ short Ps[4][16 * 74];  // per-wave P strip [q][k], stride 74

  const int qt = blockIdx.x, h = blockIdx.y, b = blockIdx.z;
  const size_t head = ((size_t)b * H_ + h) * (size_t)S_ * HD_;

  const int t = threadIdx.x;
  const int wave = t >> 6, lane = t & 63;
  const int laneN = lane & 15, quad = lane >> 4;

  // Q frags direct from global (B-operand layout)
  frag8 qf[2][2];
#pragma unroll
  for (int set = 0; set < 2; ++set) {
    const size_t row = (size_t)qt * 128 + wave * 32 + set * 16 + laneN;
#pragma unroll
    for (int half = 0; half < 2; ++half)
      qf[set][half] = ld_frag(Qf + head + row * HD_ + half * 32 + quad * 8);
  }

  f32x4 o[2][4];          // O^T: row d = dt*16+quad*4+r, col q = laneN
  float m_r[2], l_r[2];   // per-lane scalars (lane owns q = laneN per set)
#pragma unroll
  for (int st = 0; st < 2; ++st) {
    m_r[st] = -1e30f; l_r[st] = 0.f;
#pragma unroll
    for (int i = 0; i < 4; ++i)
#pragma unroll
      for (int j = 0; j < 4; ++j) o[st][i][j] = 0.f;
  }

  auto stage = [&](int buf, int kt) {
#pragma unroll
    for (int j = 0; j < 2; ++j) {
      const int chunk = j * 256 + t;
      const int row = chunk >> 3;
      const int g = (chunk & 7) ^ (row & 7);
      const int ldsoff = buf * 4096 + chunk * 8;
      async_copy16(Kf + head + (size_t)(kt * 64 + row) * HD_ + g * 8, Ks + ldsoff);
      async_copy16(Vt_ + head + (size_t)row * S_ + kt * 64 + g * 8, Vts + ldsoff);
    }
  };

  stage(0, 0);
  int buf = 0;
  for (int kt = 0; kt < 32; ++kt, buf ^= 1) {
    if (kt + 1 < 32) stage(buf ^ 1, kt + 1);
    WAITCNT_VM(4);
    RAW_BARRIER();

    // Vt frags (A-operand of PV): rows d = dt*16+laneN
    frag8 vf[4][2];
#pragma unroll
    for (int dt = 0; dt < 4; ++dt) {
      const int row = dt * 16 + laneN;
#pragma unroll
      for (int half = 0; half < 2; ++half)
        vf[dt][half] = ld_frag(Vts + buf * 4096 + row * 64 +
                               (((half * 4 + quad) ^ (row & 7)) * 8));
    }

    // S^T = K.Q^T: per lane 16 logits for q=laneN, k = nt*16+quad*4+r
    f32x4 s[2][4];
#pragma unroll
    for (int nt = 0; nt < 4; ++nt) {
      const int row = nt * 16 + laneN;
      const int o0 = buf * 4096 + row * 64 + ((quad ^ (row & 7)) * 8);
      const int o1 = buf * 4096 + row * 64 + (((quad + 4) ^ (row & 7)) * 8);
      frag8 k0 = ld_frag(Ks + o0), k1 = ld_frag(Ks + o1);
#pragma unroll
      for (int st = 0; st < 2; ++st) {
        f32x4 acc;
#pragma unroll
        for (int j = 0; j < 4; ++j) acc[j] = 0.f;
        acc = mfma_f16(k0, qf[st][0], acc);
        acc = mfma_f16(k1, qf[st][1], acc);
        s[st][nt] = acc;
      }
    }

    // online softmax per set (exp2 domain)
#pragma unroll
    for (int st = 0; st < 2; ++st) {
      float mx = -1e30f;
#pragma unroll
      for (int nt = 0; nt < 4; ++nt)
#pragma unroll
        for (int r = 0; r < 4; ++r) mx = fmaxf(mx, s[st][nt][r]);
      mx = fmaxf(mx, __shfl_xor(mx, 16));
      mx = fmaxf(mx, __shfl_xor(mx, 32));
      const float mn = fmaxf(m_r[st], mx);
      const float al = exp2f(m_r[st] - mn);
      m_r[st] = mn;
      float rs = 0.f;
#pragma unroll
      for (int nt = 0; nt < 4; ++nt)
#pragma unroll
        for (int r = 0; r < 4; ++r) {
          const float p = exp2f(s[st][nt][r] - mn);
          s[st][nt][r] = p; rs += p;
        }
      rs += __shfl_xor(rs, 16);
      rs += __shfl_xor(rs, 32);
      l_r[st] = l_r[st] * al + rs;
#pragma unroll
      for (int dt = 0; dt < 4; ++dt)
#pragma unroll
        for (int r = 0; r < 4; ++r) o[st][dt][r] *= al;

      // P pack: 4 consecutive k per nt -> one b64 LDS write; strip [q][k]
#pragma unroll
      for (int nt = 0; nt < 4; ++nt) {
        short pk[4] = { f2h(s[st][nt][0]), f2h(s[st][nt][1]),
                        f2h(s[st][nt][2]), f2h(s[st][nt][3]) };
        i32x2 w; __builtin_memcpy(&w, pk, 8);
        *(i32x2*)&Ps[wave][laneN * 74 + nt * 16 + quad * 4] = w;
      }
      // B-operand P frags: [q=laneN][k = half*32 + quad*8 ..]
      const frag8 p0 = ld_frag(&Ps[wave][laneN * 74 + quad * 8]);
      const frag8 p1 = ld_frag(&Ps[wave][laneN * 74 + 32 + quad * 8]);
#pragma unroll
      for (int dt = 0; dt < 4; ++dt) {
        o[st][dt] = mfma_f16(vf[dt][0], p0, o[st][dt]);
        o[st][dt] = mfma_f16(vf[dt][1], p1, o[st][dt]);
      }
    }
    RAW_BARRIER();
  }

  // epilogue: O^T -> Ow[B,S,D] fp16; lane owns q, 4 consecutive d per (st,dt)
#pragma unroll
  for (int st = 0; st < 2; ++st) {
    const float inv = 1.0f / l_r[st];
    const int sg = qt * 128 + wave * 32 + st * 16 + laneN;
    short* dst = Ow + ((size_t)b * S_ + sg) * D_ + h * HD_;
#pragma unroll
    for (int dt = 0; dt < 4; ++dt) {
      short pk[4] = { f2h(o[st][dt][0] * inv), f2h(o[st][dt][1] * inv),
                      f2h(o[st][dt][2] * inv), f2h(o[st][dt][3] * inv) };
      i32x2 w; __builtin_memcpy(&w, pk, 8);
      *(i32x2*)(dst + dt * 16 + quad * 4) = w;
    }
  }
}

// ---------------------------------------------------------------------------
extern "C" void kernel_launch(void* const* d_in, const int* in_sizes, int n_in,
                              void* d_out, int out_size, void* d_ws, size_t ws_size,
                              hipStream_t stream) {
  const float* q  = (const float*)d_in[0];
  const float* k  = (const float*)d_in[1];
  const float* v  = (const float*)d_in[2];
  const float* Wq = (const float*)d_in[3];
  const float* bq = (const float*)d_in[4];
  const float* Wk = (const float*)d_in[5];
  const float* bk = (const float*)d_in[6];
  const float* Wv = (const float*)d_in[7];
  const float* bv = (const float*)d_in[8];
  const float* Wo = (const float*)d_in[9];
  const float* bo = (const float*)d_in[10];

  const size_t NTOK = (size_t)B_ * S_ * D_;   // 4,194,304
  const size_t NW   = (size_t)D_ * D_;        // 1,048,576
  short* p = (short*)d_ws;
  short* qh = p; p += NTOK;  short* kh = p; p += NTOK;  short* vh = p; p += NTOK;
  short* wq = p; p += NW;    short* wk = p; p += NW;
  short* wv = p; p += NW;    short* wo = p; p += NW;
  short* Qf = p; p += NTOK;  short* Kf = p; p += NTOK;
  short* Vt = p; p += NTOK;  short* Ow = p; p += NTOK;

  dim3 blk(256);

  conv_all<<<8192, blk, 0, stream>>>(q, k, v, Wq, Wk, Wv, Wo,
                                     qh, kh, vh, wq, wk, wv, wo);

  const float QS = 11.541560327111707f;  // 8 * log2(e): exp2-domain softmax
  dim3 gqkv(D_ / 64, (B_ * S_) / 128, 3);  // (16, 32, 3) = 1536 blocks
  gemm_qkv<<<gqkv, blk, 0, stream>>>(qh, kh, vh, wq, wk, wv, bq, bk, bv,
                                     Qf, Kf, Vt, QS);

  attn<<<dim3(S_ / 128, H_, B_), blk, 0, stream>>>(Qf, Kf, Vt, Ow);

  dim3 gg(D_ / 64, (B_ * S_) / 128);  // (16, 32)
  gemm_out<<<gg, blk, 0, stream>>>(Ow, wo, bo, (float*)d_out);
}

// Round 7
// 234.782 us; speedup vs baseline: 2.1281x; 1.2065x over previous
//
#include <hip/hip_runtime.h>
#include <type_traits>
#include <utility>

#define B_ 2
#define S_ 2048
#define D_ 1024
#define H_ 16
#define HD_ 64
#define KDIM 1024

typedef __attribute__((ext_vector_type(8))) short    s16x8;
typedef __attribute__((ext_vector_type(8))) _Float16 h16x8;
typedef __attribute__((ext_vector_type(4))) float    f32x4;
typedef __attribute__((ext_vector_type(4))) int      i32x4;
typedef __attribute__((ext_vector_type(2))) int      i32x2;

// --- MFMA operand-type hedge (fp16) ---
template <typename T, typename = void> struct mfma_takes : std::false_type {};
template <typename T>
struct mfma_takes<T, std::void_t<decltype(__builtin_amdgcn_mfma_f32_16x16x32_f16(
    std::declval<T>(), std::declval<T>(), std::declval<f32x4>(), 0, 0, 0))>>
    : std::true_type {};
using frag8 = std::conditional_t<mfma_takes<h16x8>::value, h16x8, s16x8>;

__device__ __forceinline__ f32x4 mfma_f16(frag8 a, frag8 b, f32x4 c) {
  return __builtin_amdgcn_mfma_f32_16x16x32_f16(a, b, c, 0, 0, 0);
}

__device__ __forceinline__ short f2h(float f) {  // RTNE f32 -> fp16 bits
  _Float16 h = (_Float16)f;
  short s; __builtin_memcpy(&s, &h, 2);
  return s;
}
__device__ __forceinline__ frag8 ld_frag(const short* p) {
  return __builtin_bit_cast(frag8, *(const i32x4*)p);
}
__device__ __forceinline__ float fast_exp2(float x) {
  return __builtin_amdgcn_exp2f(x);
}

typedef __attribute__((address_space(1))) const void gvoid;
typedef __attribute__((address_space(3))) void lvoid;
__device__ __forceinline__ void async_copy16(const void* g, void* l) {
  __builtin_amdgcn_global_load_lds((gvoid*)g, (lvoid*)l, 16, 0, 0);
}

#define RAW_BARRIER() asm volatile("s_barrier" ::: "memory")
#define WAITCNT_VM(n) asm volatile("s_waitcnt vmcnt(" #n ")" ::: "memory")

// ---------------------------------------------------------------------------
// Fused fp32 -> fp16 converts, one launch for all 7 tensors.
// ---------------------------------------------------------------------------
__global__ __launch_bounds__(256)
void conv_all(const float* __restrict__ q, const float* __restrict__ k,
              const float* __restrict__ v, const float* __restrict__ Wq,
              const float* __restrict__ Wk, const float* __restrict__ Wv,
              const float* __restrict__ Wo,
              short* __restrict__ qh, short* __restrict__ kh,
              short* __restrict__ vh, short* __restrict__ wq,
              short* __restrict__ wk, short* __restrict__ wv,
              short* __restrict__ wo) {
  const int blk = blockIdx.x;
  const float* src; short* dst; int base;
  if (blk < 2048)      { src = q;  dst = qh; base = blk; }
  else if (blk < 4096) { src = k;  dst = kh; base = blk - 2048; }
  else if (blk < 6144) { src = v;  dst = vh; base = blk - 4096; }
  else if (blk < 6656) { src = Wq; dst = wq; base = blk - 6144; }
  else if (blk < 7168) { src = Wk; dst = wk; base = blk - 6656; }
  else if (blk < 7680) { src = Wv; dst = wv; base = blk - 7168; }
  else                 { src = Wo; dst = wo; base = blk - 7680; }
  const int i = base * 2048 + threadIdx.x * 8;
  float4 a0 = *(const float4*)(src + i);
  float4 a1 = *(const float4*)(src + i + 4);
  short h[8] = { f2h(a0.x), f2h(a0.y), f2h(a0.z), f2h(a0.w),
                 f2h(a1.x), f2h(a1.y), f2h(a1.z), f2h(a1.w) };
  i32x4 ph; __builtin_memcpy(&ph, h, 16);
  *(i32x4*)(dst + i) = ph;
}

// ---------------------------------------------------------------------------
// fp16 NT GEMM body: tile 128(M)x128(N), BK=32, double-buffered
// global_load_lds, raw s_barrier + fine vmcnt (vmcnt(0) peel on last iter),
// XOR-swizzled LDS. 4 waves, each 64x64 (4x4 16x16 tiles, 16 MFMA/iter).
// OUTK 0: fp32 flat [M,1024] (+bias).
// OUTK 1: fp16; omode 1 -> [B,H,S,Hd] (scaled, +bias); omode 2 -> Vt [B,H,Hd,S].
// ---------------------------------------------------------------------------
template <int OUTK>
__device__ __forceinline__
void gemm_body(const short* __restrict__ Ap, const short* __restrict__ Wp,
               const float* __restrict__ bias, void* __restrict__ Out,
               float scale, int omode, short* As, short* Bs, int bm, int bn) {
  const int t = threadIdx.x, wave = t >> 6, lane = t & 63;
  const int laneN = lane & 15, quad = lane >> 4;
  const int wm = wave & 1, wn = wave >> 1;

  f32x4 acc[4][4];
#pragma unroll
  for (int i = 0; i < 4; ++i)
#pragma unroll
    for (int j = 0; j < 4; ++j)
#pragma unroll
      for (int r = 0; r < 4; ++r) acc[i][j][r] = 0.f;

  auto stage = [&](int buf, int kk) {
#pragma unroll
    for (int j = 0; j < 2; ++j) {
      const int chunk = j * 256 + t;
      const int row = chunk >> 2;
      const int g = (chunk & 3) ^ ((row >> 1) & 3);
      async_copy16(Ap + (size_t)(bm * 128 + row) * KDIM + kk + g * 8,
                   As + buf * 4096 + chunk * 8);
      async_copy16(Wp + (size_t)(bn * 128 + row) * KDIM + kk + g * 8,
                   Bs + buf * 4096 + chunk * 8);
    }
  };

  stage(0, 0);
  int buf = 0;
  for (int kk = 0; kk < KDIM; kk += 32, buf ^= 1) {
    if (kk + 32 < KDIM) {
      stage(buf ^ 1, kk + 32);
      WAITCNT_VM(4);
    } else {
      WAITCNT_VM(0);
    }
    RAW_BARRIER();

    frag8 aF[4], bF[4];
#pragma unroll
    for (int mi = 0; mi < 4; ++mi) {
      const int row = wm * 64 + mi * 16 + laneN;
      aF[mi] = ld_frag(As + buf * 4096 + row * 32 +
                       ((quad ^ ((row >> 1) & 3)) * 8));
    }
#pragma unroll
    for (int ni = 0; ni < 4; ++ni) {
      const int row = wn * 64 + ni * 16 + laneN;
      bF[ni] = ld_frag(Bs + buf * 4096 + row * 32 +
                       ((quad ^ ((row >> 1) & 3)) * 8));
    }
#pragma unroll
    for (int mi = 0; mi < 4; ++mi)
#pragma unroll
      for (int ni = 0; ni < 4; ++ni)
        acc[mi][ni] = mfma_f16(aF[mi], bF[ni], acc[mi][ni]);
    RAW_BARRIER();
  }

  // Epilogue. C/D: col = lane&15, row = quad*4 + reg.
#pragma unroll
  for (int mi = 0; mi < 4; ++mi)
#pragma unroll
    for (int ni = 0; ni < 4; ++ni) {
      const int colg = bn * 128 + wn * 64 + ni * 16 + laneN;
      const float bb = bias[colg];
      if (OUTK == 1 && omode == 2) {
        // Vt [B,H,Hd,S]: r -> 4 consecutive s, same hd -> one b64 store
        const int rowg0 = bm * 128 + wm * 64 + mi * 16 + quad * 4;
        const int b = rowg0 >> 11, s0 = rowg0 & 2047;
        const int h = colg >> 6, hd = colg & 63;
        short pk[4];
#pragma unroll
        for (int r = 0; r < 4; ++r) pk[r] = f2h(acc[mi][ni][r] + bb);
        i32x2 w; __builtin_memcpy(&w, pk, 8);
        *(i32x2*)((short*)Out + (((size_t)(b * H_ + h)) * HD_ + hd) * S_ + s0) = w;
      } else {
#pragma unroll
        for (int r = 0; r < 4; ++r) {
          const int rowg = bm * 128 + wm * 64 + mi * 16 + quad * 4 + r;
          const float v = acc[mi][ni][r] + bb;
          if (OUTK == 0) {
            ((float*)Out)[(size_t)rowg * 1024 + colg] = v;
          } else {
            const int b = rowg >> 11, s = rowg & 2047;
            const int h = colg >> 6, hd = colg & 63;
            ((short*)Out)[(((size_t)(b * H_ + h)) * S_ + s) * HD_ + hd] =
                f2h(v * scale);
          }
        }
      }
    }
}

// Fused Q+K+V projections: blockIdx.z selects tensor.
__global__ __launch_bounds__(256, 3)
void gemm_qkv(const short* __restrict__ qh, const short* __restrict__ kh,
              const short* __restrict__ vh, const short* __restrict__ wq,
              const short* __restrict__ wk, const short* __restrict__ wv,
              const float* __restrict__ bq, const float* __restrict__ bk,
              const float* __restrict__ bv, short* __restrict__ Qf,
              short* __restrict__ Kf, short* __restrict__ Vt, float QS) {
  __shared__ short As[2 * 4096];
  __shared__ short Bs[2 * 4096];
  const int z = blockIdx.z;
  const short* A = z == 0 ? qh : z == 1 ? kh : vh;
  const short* W = z == 0 ? wq : z == 1 ? wk : wv;
  const float* bias = z == 0 ? bq : z == 1 ? bk : bv;
  short* Out = z == 0 ? Qf : z == 1 ? Kf : Vt;
  gemm_body<1>(A, W, bias, Out, z == 0 ? QS : 1.0f, z == 2 ? 2 : 1,
               As, Bs, blockIdx.y, blockIdx.x);
}

// O projection: fp16 A x fp16 W -> fp32 out.
__global__ __launch_bounds__(256, 3)
void gemm_out(const short* __restrict__ Ow, const short* __restrict__ wo,
              const float* __restrict__ bo, float* __restrict__ out) {
  __shared__ short As[2 * 4096];
  __shared__ short Bs[2 * 4096];
  gemm_body<0>(Ow, wo, bo, out, 1.0f, 0, As, Bs, blockIdx.y, blockIdx.x);
}

// ---------------------------------------------------------------------------
// Flash attention, fp16, 512 threads = 8 waves x 16 q-rows = 128 q/block.
// Transposed scores: mfma(A=K, B=Q) -> S^T (row=k local, col=q=laneN).
// In-lane softmax (16 regs) + 2 shuffles. PV: mfma(A=Vt, B=P) -> O^T.
// Double-buffered async K/V staging (vmcnt(0) peel on last iter),
// exp2-domain softmax (Q pre-scaled 8*log2e). LDS 50 KB -> 2 blocks/CU,
// 16 waves/CU (4/SIMD).
// ---------------------------------------------------------------------------
__global__ __launch_bounds__(512, 2)
void attn(const short* __restrict__ Qf, const short* __restrict__ Kf,
          const short* __restrict__ Vt_, short* __restrict__ Ow) {
  __shared__ short Ks[2 * 4096];
  __shared__ short Vts[2 * 4096];
  __shared__ short Ps[8][16 * 72];  // per-wave P strip [q][k], stride 72

  const int qt = blockIdx.x, h = blockIdx.y, b = blockIdx.z;
  const size_t head = ((size_t)b * H_ + h) * (size_t)S_ * HD_;

  const int t = threadIdx.x;
  const int wave = t >> 6, lane = t & 63;
  const int laneN = lane & 15, quad = lane >> 4;

  // Q frags direct from global (B-operand layout); wave owns 16 q rows
  frag8 qf[2];
  {
    const size_t row = (size_t)qt * 128 + wave * 16 + laneN;
#pragma unroll
    for (int half = 0; half < 2; ++half)
      qf[half] = ld_frag(Qf + head + row * HD_ + half * 32 + quad * 8);
  }

  f32x4 o[4];          // O^T: row d = dt*16+quad*4+r, col q = laneN
  float m_r = -1e30f, l_r = 0.f;
#pragma unroll
  for (int i = 0; i < 4; ++i)
#pragma unroll
    for (int j = 0; j < 4; ++j) o[i][j] = 0.f;

  auto stage = [&](int buf, int kt) {
    const int chunk = t;                 // 0..511
    const int row = chunk >> 3;          // 0..63
    const int g = (chunk & 7) ^ (row & 7);
    const int ldsoff = buf * 4096 + chunk * 8;
    async_copy16(Kf + head + (size_t)(kt * 64 + row) * HD_ + g * 8, Ks + ldsoff);
    async_copy16(Vt_ + head + (size_t)row * S_ + kt * 64 + g * 8, Vts + ldsoff);
  };

  stage(0, 0);
  int buf = 0;
  for (int kt = 0; kt < 32; ++kt, buf ^= 1) {
    if (kt + 1 < 32) {
      stage(buf ^ 1, kt + 1);
      WAITCNT_VM(2);
    } else {
      WAITCNT_VM(0);
    }
    RAW_BARRIER();

    // Vt frags (A-operand of PV): rows d = dt*16+laneN
    frag8 vf[4][2];
#pragma unroll
    for (int dt = 0; dt < 4; ++dt) {
      const int row = dt * 16 + laneN;
#pragma unroll
      for (int half = 0; half < 2; ++half)
        vf[dt][half] = ld_frag(Vts + buf * 4096 + row * 64 +
                               (((half * 4 + quad) ^ (row & 7)) * 8));
    }

    // S^T = K.Q^T: per lane 16 logits for q=laneN, k = nt*16+quad*4+r
    f32x4 s[4];
#pragma unroll
    for (int nt = 0; nt < 4; ++nt) {
      const int row = nt * 16 + laneN;
      const int o0 = buf * 4096 + row * 64 + ((quad ^ (row & 7)) * 8);
      const int o1 = buf * 4096 + row * 64 + (((quad + 4) ^ (row & 7)) * 8);
      frag8 k0 = ld_frag(Ks + o0), k1 = ld_frag(Ks + o1);
      f32x4 acc;
#pragma unroll
      for (int j = 0; j < 4; ++j) acc[j] = 0.f;
      acc = mfma_f16(k0, qf[0], acc);
      acc = mfma_f16(k1, qf[1], acc);
      s[nt] = acc;
    }

    // online softmax (exp2 domain): in-lane reduce 16 + xor16/xor32
    {
      float mx = -1e30f;
#pragma unroll
      for (int nt = 0; nt < 4; ++nt)
#pragma unroll
        for (int r = 0; r < 4; ++r) mx = fmaxf(mx, s[nt][r]);
      mx = fmaxf(mx, __shfl_xor(mx, 16));
      mx = fmaxf(mx, __shfl_xor(mx, 32));
      const float mn = fmaxf(m_r, mx);
      const float al = fast_exp2(m_r - mn);
      m_r = mn;
      float rs = 0.f;
#pragma unroll
      for (int nt = 0; nt < 4; ++nt)
#pragma unroll
        for (int r = 0; r < 4; ++r) {
          const float p = fast_exp2(s[nt][r] - mn);
          s[nt][r] = p; rs += p;
        }
      rs += __shfl_xor(rs, 16);
      rs += __shfl_xor(rs, 32);
      l_r = l_r * al + rs;
#pragma unroll
      for (int dt = 0; dt < 4; ++dt)
#pragma unroll
        for (int r = 0; r < 4; ++r) o[dt][r] *= al;
    }

    // P pack: 4 consecutive k per nt -> one b64 LDS write; strip [q][k]
#pragma unroll
    for (int nt = 0; nt < 4; ++nt) {
      short pk[4] = { f2h(s[nt][0]), f2h(s[nt][1]),
                      f2h(s[nt][2]), f2h(s[nt][3]) };
      i32x2 w; __builtin_memcpy(&w, pk, 8);
      *(i32x2*)&Ps[wave][laneN * 72 + nt * 16 + quad * 4] = w;
    }
    // B-operand P frags (per-wave strip; DS ops are in-order within a wave)
    const frag8 p0 = ld_frag(&Ps[wave][laneN * 72 + quad * 8]);
    const frag8 p1 = ld_frag(&Ps[wave][laneN * 72 + 32 + quad * 8]);
#pragma unroll
    for (int dt = 0; dt < 4; ++dt) {
      o[dt] = mfma_f16(vf[dt][0], p0, o[dt]);
      o[dt] = mfma_f16(vf[dt][1], p1, o[dt]);
    }
    RAW_BARRIER();
  }

  // epilogue: O^T -> Ow[B,S,D] fp16; lane owns q, 4 consecutive d per dt
  {
    const float inv = 1.0f / l_r;
    const int sg = qt * 128 + wave * 16 + laneN;
    short* dst = Ow + ((size_t)b * S_ + sg) * D_ + h * HD_;
#pragma unroll
    for (int dt = 0; dt < 4; ++dt) {
      short pk[4] = { f2h(o[dt][0] * inv), f2h(o[dt][1] * inv),
                      f2h(o[dt][2] * inv), f2h(o[dt][3] * inv) };
      i32x2 w; __builtin_memcpy(&w, pk, 8);
      *(i32x2*)(dst + dt * 16 + quad * 4) = w;
    }
  }
}

// ---------------------------------------------------------------------------
extern "C" void kernel_launch(void* const* d_in, const int* in_sizes, int n_in,
                              void* d_out, int out_size, void* d_ws, size_t ws_size,
                              hipStream_t stream) {
  const float* q  = (const float*)d_in[0];
  const float* k  = (const float*)d_in[1];
  const float* v  = (const float*)d_in[2];
  const float* Wq = (const float*)d_in[3];
  const float* bq = (const float*)d_in[4];
  const float* Wk = (const float*)d_in[5];
  const float* bk = (const float*)d_in[6];
  const float* Wv = (const float*)d_in[7];
  const float* bv = (const float*)d_in[8];
  const float* Wo = (const float*)d_in[9];
  const float* bo = (const float*)d_in[10];

  const size_t NTOK = (size_t)B_ * S_ * D_;   // 4,194,304
  const size_t NW   = (size_t)D_ * D_;        // 1,048,576
  short* p = (short*)d_ws;
  short* qh = p; p += NTOK;  short* kh = p; p += NTOK;  short* vh = p; p += NTOK;
  short* wq = p; p += NW;    short* wk = p; p += NW;
  short* wv = p; p += NW;    short* wo = p; p += NW;
  short* Qf = p; p += NTOK;  short* Kf = p; p += NTOK;
  short* Vt = p; p += NTOK;  short* Ow = p; p += NTOK;

  dim3 blk(256);

  conv_all<<<8192, blk, 0, stream>>>(q, k, v, Wq, Wk, Wv, Wo,
                                     qh, kh, vh, wq, wk, wv, wo);

  const float QS = 11.541560327111707f;  // 8 * log2(e): exp2-domain softmax
  dim3 gqkv(D_ / 128, (B_ * S_) / 128, 3);  // (8, 32, 3) = 768 blocks
  gemm_qkv<<<gqkv, blk, 0, stream>>>(qh, kh, vh, wq, wk, wv, bq, bk, bv,
                                     Qf, Kf, Vt, QS);

  attn<<<dim3(S_ / 128, H_, B_), dim3(512), 0, stream>>>(Qf, Kf, Vt, Ow);

  dim3 gg(D_ / 128, (B_ * S_) / 128);  // (8, 32)
  gemm_out<<<gg, blk, 0, stream>>>(Ow, wo, bo, (float*)d_out);
}